// Round 11
// baseline (456.948 us; speedup 1.0000x reference)
//
#include <hip/hip_runtime.h>
#include <math.h>

#define NN 50000
#define EE 800000
#define HH 64
#define RR 8
#define LL 3
#define NR (NN * RR)            // 400000 segments
#define NB ((NR + 255) / 256)   // 1563 scan blocks
#define LN_EPS 1e-5f
#define NEG_SLOPE 0.2f
#define LDH 68                  // fp32 row stride for t/o tiles in reused psL
#define OTB (16 * LDH)          // o-tile base (floats) inside ps_f
#define DSPREAD 64              // denom partial rows (distinct cachelines)
#define NPB 80                  // nodes per combine block (50000 = 625*80)
#define NGRP 5                  // 16-node groups per combine block

typedef __attribute__((ext_vector_type(8))) short bf8;
typedef __attribute__((ext_vector_type(4))) float f4;
typedef __attribute__((ext_vector_type(2))) float f2;
typedef __attribute__((ext_vector_type(8))) unsigned short us8;
typedef __attribute__((ext_vector_type(2))) unsigned int u2;
typedef __attribute__((ext_vector_type(4))) unsigned int u4;

// inline-asm W-fragment pair load (volatile: cannot be sunk/remat — the
// r3/r4/r5 failure mode). HAZARD (r10 post-mortem): outputs are asm results
// the compiler may spill BEFORE the loads land. MUST be followed by an
// explicit hardware s_waitcnt vmcnt(0) before any spillable region.
#define WLOADP(d0, d1, sbase, vbyte) \
    asm volatile("global_load_dwordx4 %0, %2, %3 offset:0\n\t" \
                 "global_load_dwordx4 %1, %2, %3 offset:64" \
        : "=&v"(d0), "=&v"(d1) : "v"(vbyte), "s"(sbase) : "memory")

__device__ __forceinline__ unsigned short bf16r(float f) {
    unsigned u = __float_as_uint(f);
    unsigned r = u + 0x7fffu + ((u >> 16) & 1u);
    return (unsigned short)(r >> 16);
}
__device__ __forceinline__ float bf2f(unsigned short u) {
    return __uint_as_float(((unsigned)u) << 16);
}
__device__ __forceinline__ bf8 asbf8(u4 v) {
    union { u4 a; bf8 b; } c; c.a = v; return c.b;
}
// fire-and-forget 16B global->LDS; completion via __syncthreads vmcnt drain.
__device__ __forceinline__ void stage16(const void* g, void* l) {
    __builtin_amdgcn_global_load_lds(
        (const __attribute__((address_space(1))) void*)g,
        (__attribute__((address_space(3))) void*)l, 16, 0, 0);
}

// 16-node blocks: h = relu(x @ W_in^T + b_in) in fp32 via LDS;
// emit bf16 gather mirror; wave 0 computes s_src/s_dst via 2 MFMAs (WaB).
__global__ __launch_bounds__(256) void proj_in(
    const float* __restrict__ x, const float* __restrict__ W,
    const float* __restrict__ bias, const unsigned short* __restrict__ WaB,
    float* __restrict__ h, unsigned short* __restrict__ hbf,
    float* __restrict__ s_src, float* __restrict__ s_dst) {
    __shared__ float WT[64 * LDH];     // WT[i][k] = W[k][i]
    __shared__ float xs[16 * LDH];
    __shared__ float hs[16 * LDH];
    int tid = threadIdx.x;
    int n0 = blockIdx.x * 16;          // NN % 16 == 0
    #pragma unroll
    for (int s = 0; s < 16; ++s) {
        int idx = tid + 256 * s;
        int k = idx >> 6, i = idx & 63;
        WT[i * LDH + k] = W[idx];
    }
    int row = tid >> 4, cg = tid & 15;
    {
        f4 v = ((const f4*)x)[(size_t)(n0 + row) * 16 + cg];
        *(f4*)&xs[row * LDH + cg * 4] = v;
    }
    __syncthreads();
    f4 acc;
    {
        f4 b = *(const f4*)(bias + cg * 4);
        acc = b;
        #pragma unroll
        for (int i = 0; i < 64; ++i) {
            float xv = xs[row * LDH + i];
            f4 wt = *(const f4*)&WT[i * LDH + cg * 4];
            acc[0] += xv * wt[0];
            acc[1] += xv * wt[1];
            acc[2] += xv * wt[2];
            acc[3] += xv * wt[3];
        }
        #pragma unroll
        for (int j = 0; j < 4; ++j) acc[j] = fmaxf(acc[j], 0.f);
        int n = n0 + row;
        *(f4*)(h + (size_t)n * 64 + cg * 4) = acc;
        u2 u;
        u[0] = (unsigned)bf16r(acc[0]) | ((unsigned)bf16r(acc[1]) << 16);
        u[1] = (unsigned)bf16r(acc[2]) | ((unsigned)bf16r(acc[3]) << 16);
        *(u2*)(hbf + (size_t)n * 64 + cg * 4) = u;
        *(f4*)&hs[row * LDH + cg * 4] = acc;
    }
    __syncthreads();
    if (tid < 64) {      // wave 0: attention pre-scores via MFMA
        int lane = tid;
        int quad = lane >> 4, lr = lane & 15;
        f4 sc = (f4){0.f, 0.f, 0.f, 0.f};
        #pragma unroll
        for (int kb = 0; kb < 2; ++kb) {
            const float* p = &hs[lr * LDH + kb * 32 + quad * 8];
            bf8 a;
            #pragma unroll
            for (int j = 0; j < 8; ++j) a[j] = (short)bf16r(p[j]);
            const bf8* bw = (const bf8*)(WaB + lr * 64 + kb * 32 + quad * 8);
            sc = __builtin_amdgcn_mfma_f32_16x16x32_bf16(a, *bw, sc, 0, 0, 0);
        }
        #pragma unroll
        for (int j = 0; j < 4; ++j) {
            int n = n0 + quad * 4 + j;
            if (lr < 8) s_src[n * 8 + lr] = sc[j];
            else        s_dst[n * 8 + (lr - 8)] = sc[j];
        }
    }
}

// ---- one-time CSR build (compact, exact) ----
__global__ void edge_count(const int* __restrict__ ei, const int* __restrict__ et,
                           int* __restrict__ counts, int* __restrict__ rank) {
    int e = blockIdx.x * 256 + threadIdx.x;
    int d = ei[EE + e], t = et[e];
    rank[e] = atomicAdd(&counts[d * 8 + t], 1);
}

__global__ void scan1(const int* __restrict__ counts, int* __restrict__ offs,
                      int* __restrict__ bsum) {
    __shared__ int s[256];
    int tid = threadIdx.x;
    int i = blockIdx.x * 256 + tid;
    int v = (i < NR) ? counts[i] : 0;
    s[tid] = v; __syncthreads();
    for (int d = 1; d < 256; d <<= 1) {
        int x = (tid >= d) ? s[tid - d] : 0;
        __syncthreads();
        s[tid] += x;
        __syncthreads();
    }
    if (i < NR) offs[i] = s[tid] - v;   // local (per-block) exclusive prefix
    if (tid == 255) bsum[blockIdx.x] = s[255];
}

__global__ void scan2(int* __restrict__ bsum) {   // 1024 threads, 2 chunks
    __shared__ int s[1024];
    int tid = threadIdx.x;
    int carry = 0;
    for (int c0 = 0; c0 < NB; c0 += 1024) {
        int i = c0 + tid;
        int v = (i < NB) ? bsum[i] : 0;
        s[tid] = v; __syncthreads();
        for (int d = 1; d < 1024; d <<= 1) {
            int x = (tid >= d) ? s[tid - d] : 0;
            __syncthreads();
            s[tid] += x;
            __syncthreads();
        }
        if (i < NB) bsum[i] = carry + s[tid] - v;
        int tot = s[1023];
        __syncthreads();
        carry += tot;
    }
}

// spack[slot] = {src, seg}; slot = offs[seg] + bsum[seg>>8] + rank
__global__ void edge_fill(const int* __restrict__ ei, const int* __restrict__ et,
                          const int* __restrict__ rank, const int* __restrict__ offs,
                          const int* __restrict__ bsum, u2* __restrict__ spack) {
    int e = blockIdx.x * 256 + threadIdx.x;
    int s = ei[e], d = ei[EE + e], t = et[e];
    int seg = d * 8 + t;
    int slot = offs[seg] + bsum[seg >> 8] + rank[e];
    spack[slot] = (u2){(unsigned)s, (unsigned)seg};
}

// weights -> bf16: WrB/WgB [r][kout][kd]; WaB [16][64]; WoB [kout][kd]
__global__ void cvt_w(const float* __restrict__ Wr, const float* __restrict__ Wg,
                      const float* __restrict__ Wa, const float* __restrict__ Wo,
                      unsigned short* __restrict__ WrB, unsigned short* __restrict__ WgB,
                      unsigned short* __restrict__ WaB, unsigned short* __restrict__ WoB) {
    int i = blockIdx.x * 256 + threadIdx.x;   // 32768 total
    WrB[i] = bf16r(Wr[i]);
    WgB[i] = bf16r(Wg[i]);
    if (i < 1024) {
        int row = i >> 6, k = i & 63;
        float v = (row < 8) ? Wa[row * 128 + k] : Wa[(row - 8) * 128 + 64 + k];
        WaB[i] = bf16r(v);
    }
    if (i < 4096) WoB[i] = bf16r(Wo[i]);
}

// per-type denom partials (edge-parallel): streams spack, ex inline, dpart.
__global__ void denom_pass(const u2* __restrict__ spack,
                           const float* __restrict__ s_src,
                           const float* __restrict__ s_dst,
                           const float* __restrict__ b_att,
                           float* __restrict__ dpart) {
    __shared__ float lsum[4][8];
    int tid = threadIdx.x;
    if (tid < 32) lsum[tid >> 3][tid & 7] = 0.f;
    __syncthreads();
    int slot = blockIdx.x * 256 + tid;     // EE % 256 == 0
    u2 sp = spack[slot];
    int src = (int)sp[0];
    int seg = (int)sp[1];
    int t = seg & 7;
    float sc = s_src[src * 8 + t] + s_dst[seg] + b_att[t];
    sc = (sc >= 0.f) ? sc : NEG_SLOPE * sc;
    float ex = __expf(sc);
    atomicAdd(&lsum[tid >> 6][t], ex);
    __syncthreads();
    if (tid < 8) {
        float v = lsum[0][tid] + lsum[1][tid] + lsum[2][tid] + lsum[3][tid];
        atomicAdd(&dpart[(blockIdx.x & (DSPREAD - 1)) * 16 + tid], v);
    }
}

// one-block reduce: dpart (64 rows x 16, types 0..7) -> idn8 = 1/sum
__global__ void denom_reduce(const float* __restrict__ dpartL,
                             float* __restrict__ idn8L) {
    __shared__ float sb[256];
    int t = threadIdx.x;
    int rb = t >> 3, ty = t & 7;
    float v = dpartL[rb * 16 + ty] + dpartL[(rb + 32) * 16 + ty];
    sb[t] = v; __syncthreads();
    for (int st = 128; st >= 8; st >>= 1) {
        if (t < st) sb[t] += sb[t + st];
        __syncthreads();
    }
    if (t < 8) idn8L[t] = 1.f / sb[t];
}

// inline per-group gather: thread = (segment segl, 32-col half); computes ex
// inline (fused softmax), register-accumulates UNNORMALIZED agg (unroll-2,
// r11: reduced from 4 to relieve VGPR pressure inside the W live range),
// packs bf16, ds_writes into psL with the (chunk ^ gn&7) swizzle — image is
// byte-identical to r9's staged psG slice. Normalization stays post-MFMA.
__device__ __forceinline__ void gather_group(
    int sidx0, int segl, int half,
    const int* __restrict__ offs, const int* __restrict__ bsum,
    const u2* __restrict__ spack, const float* __restrict__ s_src,
    const float* __restrict__ s_dst, float bav,
    const unsigned short* __restrict__ hbf_in,
    unsigned short* psb) {
    int sidx = sidx0 + segl;
    int lo = offs[sidx] + bsum[sidx >> 8];
    int nxt = sidx + 1;
    int hi = (nxt < NR) ? (offs[nxt] + bsum[nxt >> 8]) : EE;
    int r = segl & 7, gn = segl >> 3;
    float bconst = s_dst[sidx] + bav;

    f2 acc[16];
    #pragma unroll
    for (int i = 0; i < 16; ++i) acc[i] = (f2){0.f, 0.f};

    for (int s = lo; s < hi; s += 2) {
        int i1 = (s + 1 < hi) ? s + 1 : s;
        u2 sp0 = spack[s], sp1 = spack[i1];
        int sr0 = (int)sp0[0], sr1 = (int)sp1[0];
        float sc0 = s_src[sr0 * 8 + r] + bconst;
        float sc1 = s_src[sr1 * 8 + r] + bconst;
        sc0 = (sc0 >= 0.f) ? sc0 : NEG_SLOPE * sc0;
        sc1 = (sc1 >= 0.f) ? sc1 : NEG_SLOPE * sc1;
        float a0 = __expf(sc0);
        float a1 = (s + 1 < hi) ? __expf(sc1) : 0.f;
        const u4* hp0 = (const u4*)(hbf_in + ((size_t)sr0 << 6) + half * 32);
        const u4* hp1 = (const u4*)(hbf_in + ((size_t)sr1 << 6) + half * 32);
        #pragma unroll
        for (int q = 0; q < 4; ++q) {
            u4 v0 = hp0[q], v1 = hp1[q];
            #pragma unroll
            for (int k = 0; k < 4; ++k) {
                f2 w0, w1;
                w0[0] = __uint_as_float(v0[k] << 16);
                w0[1] = __uint_as_float(v0[k] & 0xffff0000u);
                w1[0] = __uint_as_float(v1[k] << 16);
                w1[1] = __uint_as_float(v1[k] & 0xffff0000u);
                acc[q * 4 + k] += (f2){a0, a0} * w0;
                acc[q * 4 + k] += (f2){a1, a1} * w1;
            }
        }
    }

    unsigned short* base = psb + gn * 512 + r * 64;
    #pragma unroll
    for (int q = 0; q < 4; ++q) {
        us8 o;
        #pragma unroll
        for (int k = 0; k < 4; ++k) {
            o[2 * k]     = bf16r(acc[q * 4 + k][0]);
            o[2 * k + 1] = bf16r(acc[q * 4 + k][1]);
        }
        int c2 = (half * 4 + q) ^ (gn & 7);
        *(us8*)(base + c2 * 8) = o;
    }
}

// stage hbuf fp32 tile for group g into hsL[b] (src-swizzled, 1 op/thread)
#define STAGE_HS(b, g) do { \
    int n0s_ = nb0 + (g) * 16; \
    unsigned a_ = (unsigned)(w * 1024 + lane * 16); \
    unsigned sa_ = a_ ^ (((a_ >> 8) & 7u) << 4); \
    stage16((const float*)((const char*)(hbuf + (size_t)n0s_ * 64) + sa_), \
            (char*)hsL[b] + a_); \
} while (0)

// K2: FUSED gather+combine v11 — v10 + the W-load landing fix.
// Per iter g: [stage hsL(g+1) async; INLINE gather(g+1) -> ds_write
// psL[cb^1]] then MFMA(g) + epilogue. psG eliminated.
// r11 FIX: explicit s_waitcnt vmcnt(0) right after the W-load batch — the
// asm outputs must LAND before the compiler's spill code can touch them
// (r10 failed: W regs spilled pre-landing under gather's register pressure).
template<bool EMIT, bool OUT>
__global__ __launch_bounds__(256, 2) void combine_fused(
    const float* __restrict__ hbuf, const unsigned short* __restrict__ hbf_in,
    const float* __restrict__ idn8L,
    const int* __restrict__ offs, const int* __restrict__ bsum,
    const u2* __restrict__ spack, const float* __restrict__ s_srcI,
    const float* __restrict__ s_dstI, const float* __restrict__ b_att,
    const unsigned short* __restrict__ WrB, const unsigned short* __restrict__ WgB,
    const unsigned short* __restrict__ WaB, const unsigned short* __restrict__ WoB,
    const float* __restrict__ b_gate, const float* __restrict__ gamma,
    const float* __restrict__ beta, float* __restrict__ hout,
    unsigned short* __restrict__ hbf_out, float* __restrict__ ssrc_out,
    float* __restrict__ sdst_out, float* __restrict__ outp,
    const float* __restrict__ b_out) {
    __shared__ alignas(16) unsigned short psL[2][8192]; // 2x16KB agg / fp32 scratch
    __shared__ alignas(16) float hsL[2][1024];          // 2x4KB h tiles (swizzled)
    int tid = threadIdx.x;
    int nb0 = blockIdx.x * NPB;
    int w = tid >> 6, lane = tid & 63;
    int quad = lane >> 4, lr = lane & 15;
    int tn = w;
    int segl = tid >> 1, half = tid & 1;

    // prologue stage first (its vmcnt is drained by the wait below too)
    STAGE_HS(0, 0);

    // W fragments once per block (volatile asm; resident for all 5 groups)
    unsigned rowb = (unsigned)((tn * 16 + lr) * 128 + quad * 16);
    u4 wr[8][2], wg[8][2];
    #pragma unroll
    for (int r = 0; r < 8; ++r) {
        WLOADP(wr[r][0], wr[r][1], WrB, rowb + (unsigned)r * 8192u);
        WLOADP(wg[r][0], wg[r][1], WgB, rowb + (unsigned)r * 8192u);
    }
    float bgv[8];
    #pragma unroll
    for (int r = 0; r < 8; ++r) bgv[r] = b_gate[r * 64 + tn * 16 + lr];
    f4 gmv = *(const f4*)(gamma + (tid & 15) * 4);
    f4 btv = *(const f4*)(beta + (tid & 15) * 4);
    f4 id0 = *(const f4*)idn8L;
    f4 id1 = *(const f4*)(idn8L + 4);
    float idnv[8] = {id0[0], id0[1], id0[2], id0[3],
                     id1[0], id1[1], id1[2], id1[3]};
    float bav = b_att[segl & 7];   // per-thread attention bias (r fixed)

    // LAND the asm W loads before any spillable region (r10 fix)
    asm volatile("s_waitcnt vmcnt(0)" ::: "memory");
    __builtin_amdgcn_sched_barrier(0);

    // prologue gather group 0
    gather_group(nb0 * 8, segl, half, offs, bsum, spack, s_srcI, s_dstI,
                 bav, hbf_in, psL[0]);

    for (int g = 0; g < NGRP; ++g) {
        int cb = g & 1;
        int n0 = nb0 + g * 16;
        __syncthreads();   // psL[cb] gather-writes + hsL[cb] stage complete

        if (g + 1 < NGRP) {
            STAGE_HS(cb ^ 1, g + 1);       // async; drains at a later sync
            gather_group((nb0 + (g + 1) * 16) * 8, segl, half, offs, bsum,
                         spack, s_srcI, s_dstI, bav, hbf_in, psL[cb ^ 1]);
        }

        // A_h fragments from hsL[cb] (swizzled chunks)
        bf8 a_h[2];
        #pragma unroll
        for (int kb = 0; kb < 2; ++kb) {
            unsigned c0 = (unsigned)(kb * 8 + quad * 2)     ^ (unsigned)(lr & 7);
            unsigned c1 = (unsigned)(kb * 8 + quad * 2 + 1) ^ (unsigned)(lr & 7);
            f4 p0 = *(const f4*)((const char*)hsL[cb] + lr * 256 + c0 * 16);
            f4 p1 = *(const f4*)((const char*)hsL[cb] + lr * 256 + c1 * 16);
            bf8 a;
            #pragma unroll
            for (int j = 0; j < 4; ++j) a[j] = (short)bf16r(p0[j]);
            #pragma unroll
            for (int j = 0; j < 4; ++j) a[4 + j] = (short)bf16r(p1[j]);
            a_h[kb] = a;
        }

        // 8 relation MFMA phases (W from regs; a_p from psL[cb])
        f4 acc = (f4){0.f, 0.f, 0.f, 0.f};
        #pragma unroll
        for (int r = 0; r < 8; ++r) {
            bf8 a_p[2];
            #pragma unroll
            for (int kb = 0; kb < 2; ++kb) {
                unsigned c = (unsigned)(kb * 4 + quad) ^ (unsigned)(lr & 7);
                a_p[kb] = *(const bf8*)((const char*)psL[cb] + lr * 1024 + r * 128 + c * 16);
            }
            f4 aggc = (f4){0.f, 0.f, 0.f, 0.f};
            f4 gacc = (f4){0.f, 0.f, 0.f, 0.f};
            aggc = __builtin_amdgcn_mfma_f32_16x16x32_bf16(a_p[0], asbf8(wr[r][0]), aggc, 0, 0, 0);
            gacc = __builtin_amdgcn_mfma_f32_16x16x32_bf16(a_h[0], asbf8(wg[r][0]), gacc, 0, 0, 0);
            aggc = __builtin_amdgcn_mfma_f32_16x16x32_bf16(a_p[1], asbf8(wr[r][1]), aggc, 0, 0, 0);
            gacc = __builtin_amdgcn_mfma_f32_16x16x32_bf16(a_h[1], asbf8(wg[r][1]), gacc, 0, 0, 0);
            #pragma unroll
            for (int j = 0; j < 4; ++j) {
                float gt = 1.f / (1.f + __expf(-(gacc[j] + bgv[r])));
                acc[j] += gt * (aggc[j] * idnv[r]);   // normalization (fp32)
            }
        }
        __syncthreads();   // all waves done reading psL[cb] -> reuse as fp32

        float* ps_f = (float*)psL[cb];
        // t = h + acc/8 into ps_f rows 0..15; residual from swizzled hsL[cb]
        #pragma unroll
        for (int j = 0; j < 4; ++j) {
            int row = quad * 4 + j;
            int col = tn * 16 + lr;
            unsigned y = (unsigned)(row * 256 + col * 4);
            float hres = *(const float*)((const char*)hsL[cb] + (y ^ (((unsigned)(row & 7)) << 4)));
            ps_f[row * LDH + col] = hres + acc[j] * 0.125f;
        }
        __syncthreads();

        // LN + ReLU; o-tile into ps_f[OTB..) (disjoint region)
        {
            int row = tid >> 4, c = tid & 15;
            int n = n0 + row;
            f4 tv = *(const f4*)&ps_f[row * LDH + c * 4];
            float s1 = tv[0] + tv[1] + tv[2] + tv[3];
            float s2 = tv[0]*tv[0] + tv[1]*tv[1] + tv[2]*tv[2] + tv[3]*tv[3];
            #pragma unroll
            for (int off = 1; off <= 8; off <<= 1) {
                s1 += __shfl_xor(s1, off, 64);
                s2 += __shfl_xor(s2, off, 64);
            }
            float mu = s1 * (1.f / 64.f);
            float var = s2 * (1.f / 64.f) - mu * mu;
            float rs = rsqrtf(var + LN_EPS);
            f4 ov;
            #pragma unroll
            for (int j = 0; j < 4; ++j)
                ov[j] = fmaxf((tv[j] - mu) * rs * gmv[j] + btv[j], 0.f);
            if (!OUT)
                *(f4*)(hout + (size_t)n * 64 + c * 4) = ov;
            *(f4*)&ps_f[OTB + row * LDH + c * 4] = ov;
            if (EMIT) {
                u2 u;
                u[0] = (unsigned)bf16r(ov[0]) | ((unsigned)bf16r(ov[1]) << 16);
                u[1] = (unsigned)bf16r(ov[2]) | ((unsigned)bf16r(ov[3]) << 16);
                *(u2*)(hbf_out + (size_t)n * 64 + c * 4) = u;
            }
        }

        if (EMIT) {
            __syncthreads();
            if (w == 0) {   // next-layer attention pre-scores
                f4 sc = (f4){0.f, 0.f, 0.f, 0.f};
                #pragma unroll
                for (int kb = 0; kb < 2; ++kb) {
                    const float* p = &ps_f[OTB + lr * LDH + kb * 32 + quad * 8];
                    bf8 a;
                    #pragma unroll
                    for (int j = 0; j < 8; ++j) a[j] = (short)bf16r(p[j]);
                    const bf8* bw = (const bf8*)(WaB + lr * 64 + kb * 32 + quad * 8);
                    sc = __builtin_amdgcn_mfma_f32_16x16x32_bf16(a, *bw, sc, 0, 0, 0);
                }
                #pragma unroll
                for (int j = 0; j < 4; ++j) {
                    int n = n0 + quad * 4 + j;
                    if (lr < 8) ssrc_out[n * 8 + lr] = sc[j];
                    else        sdst_out[n * 8 + (lr - 8)] = sc[j];
                }
            }
        }

        if (OUT) {
            __syncthreads();
            f4 oc = (f4){0.f, 0.f, 0.f, 0.f};
            #pragma unroll
            for (int kb = 0; kb < 2; ++kb) {
                const float* p = &ps_f[OTB + lr * LDH + kb * 32 + quad * 8];
                bf8 a;
                #pragma unroll
                for (int j = 0; j < 8; ++j) a[j] = (short)bf16r(p[j]);
                const bf8* bw = (const bf8*)(WoB + ((tn * 16 + lr) * 64 + kb * 32 + quad * 8));
                oc = __builtin_amdgcn_mfma_f32_16x16x32_bf16(a, *bw, oc, 0, 0, 0);
            }
            float bo = b_out[tn * 16 + lr];
            #pragma unroll
            for (int j = 0; j < 4; ++j)
                outp[(size_t)(n0 + quad * 4 + j) * 64 + tn * 16 + lr] = oc[j] + bo;
        }
        // iter-(g+1) top __syncthreads separates epilogue's ps_f use from
        // gather(g+2)'s overwrite of the same buffer
    }
}

extern "C" void kernel_launch(void* const* d_in, const int* in_sizes, int n_in,
                              void* d_out, int out_size, void* d_ws, size_t ws_size,
                              hipStream_t stream) {
    const float* x      = (const float*)d_in[0];
    const int*   ei     = (const int*)d_in[1];
    const int*   et     = (const int*)d_in[2];
    const float* W_in   = (const float*)d_in[3];
    const float* b_in   = (const float*)d_in[4];
    const float* W_rel  = (const float*)d_in[5];
    const float* W_gate = (const float*)d_in[6];
    const float* b_gate = (const float*)d_in[7];
    const float* W_att  = (const float*)d_in[8];
    const float* b_att  = (const float*)d_in[9];
    const float* ln_g   = (const float*)d_in[10];
    const float* ln_b   = (const float*)d_in[11];
    const float* W_out  = (const float*)d_in[12];
    const float* b_out  = (const float*)d_in[13];
    float* out = (float*)d_out;

    float* h0 = (float*)d_out;          // ping-pong A (scratch until final layer)

    char* ws = (char*)d_ws;
    float* h1 = (float*)ws;                     ws += (size_t)NN * 64 * 4;
    unsigned short* hbfA = (unsigned short*)ws; ws += (size_t)NN * 64 * 2;
    unsigned short* hbfB = (unsigned short*)ws; ws += (size_t)NN * 64 * 2;
    float* s_srcA = (float*)ws;                 ws += (size_t)NN * 8 * 4;
    float* s_dstA = (float*)ws;                 ws += (size_t)NN * 8 * 4;
    float* s_srcB = (float*)ws;                 ws += (size_t)NN * 8 * 4;
    float* s_dstB = (float*)ws;                 ws += (size_t)NN * 8 * 4;
    unsigned short* WrB = (unsigned short*)ws;  ws += (size_t)RR * 64 * 64 * 2;
    unsigned short* WgB = (unsigned short*)ws;  ws += (size_t)RR * 64 * 64 * 2;
    unsigned short* WaB = (unsigned short*)ws;  ws += 2048;
    unsigned short* WoB = (unsigned short*)ws;  ws += 8192;
    // contiguous zero region: counts + 3 per-layer dpart regions
    int* counts = (int*)ws;                     ws += (size_t)NR * 4;
    float* dpart = (float*)ws;                  ws += 3 * DSPREAD * 16 * 4;
    float* idn8G = (float*)ws;                  ws += 3 * 16 * 4;   // 8 used/layer
    int* offs = (int*)ws;                       ws += (size_t)NR * 4;
    int* bsum = (int*)ws;                       ws += 6400;
    int* rank = (int*)ws;                       ws += (size_t)EE * 4;
    u2* spack = (u2*)ws;                        ws += (size_t)EE * 8;

    hipMemsetAsync(counts, 0, (size_t)NR * 4 + 3 * DSPREAD * 16 * 4, stream);
    cvt_w<<<128, 256, 0, stream>>>(W_rel, W_gate, W_att, W_out, WrB, WgB, WaB, WoB);
    edge_count<<<EE / 256, 256, 0, stream>>>(ei, et, counts, rank);
    scan1<<<NB, 256, 0, stream>>>(counts, offs, bsum);
    scan2<<<1, 1024, 0, stream>>>(bsum);
    edge_fill<<<EE / 256, 256, 0, stream>>>(ei, et, rank, offs, bsum, spack);
    proj_in<<<NN / 16, 256, 0, stream>>>(x, W_in, b_in, WaB, h0, hbfA, s_srcA, s_dstA);

    const int tiles80 = NN / NPB;   // 625 (combine grid)
    float* hA = h0;  float* hB = h1;
    unsigned short* bfA = hbfA;  unsigned short* bfB = hbfB;
    float* ssI = s_srcA;  float* sdI = s_dstA;
    float* ssO = s_srcB;  float* sdO = s_dstB;
    for (int layer = 0; layer < LL; ++layer) {
        float* dpl = dpart + (size_t)layer * DSPREAD * 16;
        float* idn = idn8G + (size_t)layer * 16;
        denom_pass<<<EE / 256, 256, 0, stream>>>(spack, ssI, sdI, b_att, dpl);
        denom_reduce<<<1, 256, 0, stream>>>(dpl, idn);
        if (layer < LL - 1) {
            combine_fused<true, false><<<tiles80, 256, 0, stream>>>(
                hA, bfA, idn, offs, bsum, spack, ssI, sdI, b_att,
                WrB, WgB, WaB, WoB, b_gate,
                ln_g + layer * 64, ln_b + layer * 64,
                hB, bfB, ssO, sdO, out, b_out);
        } else {
            combine_fused<false, true><<<tiles80, 256, 0, stream>>>(
                hA, bfA, idn, offs, bsum, spack, ssI, sdI, b_att,
                WrB, WgB, WaB, WoB, b_gate,
                ln_g + layer * 64, ln_b + layer * 64,
                hB, bfB, ssO, sdO, out, b_out);
        }
        float* tf = hA; hA = hB; hB = tf;
        unsigned short* tb = bfA; bfA = bfB; bfB = tb;
        float* ts = ssI; ssI = ssO; ssO = ts;
        float* td = sdI; sdI = sdO; sdO = td;
    }
}

// Round 12
// 415.203 us; speedup vs baseline: 1.1005x; 1.1005x over previous
//
#include <hip/hip_runtime.h>
#include <math.h>

#define NN 50000
#define EE 800000
#define HH 64
#define RR 8
#define LL 3
#define NR (NN * RR)            // 400000 segments
#define NB ((NR + 255) / 256)   // 1563 scan blocks
#define LN_EPS 1e-5f
#define NEG_SLOPE 0.2f
#define LDH 68                  // fp32 row stride for t/o tiles in reused psL
#define OTB (16 * LDH)          // o-tile base (floats) inside ps_f
#define DSPREAD 64              // denom partial rows (distinct cachelines)
#define NPB 80                  // nodes per combine block (50000 = 625*80)
#define NGRP 5                  // 16-node groups per combine block

typedef __attribute__((ext_vector_type(8))) short bf8;
typedef __attribute__((ext_vector_type(4))) float f4;
typedef __attribute__((ext_vector_type(2))) float f2;
typedef __attribute__((ext_vector_type(8))) unsigned short us8;
typedef __attribute__((ext_vector_type(2))) unsigned int u2;
typedef __attribute__((ext_vector_type(4))) unsigned int u4;

// inline-asm W-fragment pair load: volatile => cannot be sunk/rematerialized
// (the r3/r4/r5 failure mode). Loaded ONCE per block, reused across 5 groups.
// Landing guarantee: the first counted s_waitcnt in the group loop retires
// these before any use (r8-verified correct).
#define WLOADP(d0, d1, sbase, vbyte) \
    asm volatile("global_load_dwordx4 %0, %2, %3 offset:0\n\t" \
                 "global_load_dwordx4 %1, %2, %3 offset:64" \
        : "=&v"(d0), "=&v"(d1) : "v"(vbyte), "s"(sbase) : "memory")

__device__ __forceinline__ unsigned short bf16r(float f) {
    unsigned u = __float_as_uint(f);
    unsigned r = u + 0x7fffu + ((u >> 16) & 1u);
    return (unsigned short)(r >> 16);
}
__device__ __forceinline__ float bf2f(unsigned short u) {
    return __uint_as_float(((unsigned)u) << 16);
}
__device__ __forceinline__ bf8 asbf8(u4 v) {
    union { u4 a; bf8 b; } c; c.a = v; return c.b;
}
// fire-and-forget 16B global->LDS; completion via vmcnt accounting.
__device__ __forceinline__ void stage16(const void* g, void* l) {
    __builtin_amdgcn_global_load_lds(
        (const __attribute__((address_space(1))) void*)g,
        (__attribute__((address_space(3))) void*)l, 16, 0, 0);
}

// 16-node blocks: h = relu(x @ W_in^T + b_in) in fp32 via LDS;
// emit bf16 gather mirror; wave 0 computes s_src/s_dst via 2 MFMAs (WaB).
__global__ __launch_bounds__(256) void proj_in(
    const float* __restrict__ x, const float* __restrict__ W,
    const float* __restrict__ bias, const unsigned short* __restrict__ WaB,
    float* __restrict__ h, unsigned short* __restrict__ hbf,
    float* __restrict__ s_src, float* __restrict__ s_dst) {
    __shared__ float WT[64 * LDH];     // WT[i][k] = W[k][i]
    __shared__ float xs[16 * LDH];
    __shared__ float hs[16 * LDH];
    int tid = threadIdx.x;
    int n0 = blockIdx.x * 16;          // NN % 16 == 0
    #pragma unroll
    for (int s = 0; s < 16; ++s) {
        int idx = tid + 256 * s;
        int k = idx >> 6, i = idx & 63;
        WT[i * LDH + k] = W[idx];
    }
    int row = tid >> 4, cg = tid & 15;
    {
        f4 v = ((const f4*)x)[(size_t)(n0 + row) * 16 + cg];
        *(f4*)&xs[row * LDH + cg * 4] = v;
    }
    __syncthreads();
    f4 acc;
    {
        f4 b = *(const f4*)(bias + cg * 4);
        acc = b;
        #pragma unroll
        for (int i = 0; i < 64; ++i) {
            float xv = xs[row * LDH + i];
            f4 wt = *(const f4*)&WT[i * LDH + cg * 4];
            acc[0] += xv * wt[0];
            acc[1] += xv * wt[1];
            acc[2] += xv * wt[2];
            acc[3] += xv * wt[3];
        }
        #pragma unroll
        for (int j = 0; j < 4; ++j) acc[j] = fmaxf(acc[j], 0.f);
        int n = n0 + row;
        *(f4*)(h + (size_t)n * 64 + cg * 4) = acc;
        u2 u;
        u[0] = (unsigned)bf16r(acc[0]) | ((unsigned)bf16r(acc[1]) << 16);
        u[1] = (unsigned)bf16r(acc[2]) | ((unsigned)bf16r(acc[3]) << 16);
        *(u2*)(hbf + (size_t)n * 64 + cg * 4) = u;
        *(f4*)&hs[row * LDH + cg * 4] = acc;
    }
    __syncthreads();
    if (tid < 64) {      // wave 0: attention pre-scores via MFMA
        int lane = tid;
        int quad = lane >> 4, lr = lane & 15;
        f4 sc = (f4){0.f, 0.f, 0.f, 0.f};
        #pragma unroll
        for (int kb = 0; kb < 2; ++kb) {
            const float* p = &hs[lr * LDH + kb * 32 + quad * 8];
            bf8 a;
            #pragma unroll
            for (int j = 0; j < 8; ++j) a[j] = (short)bf16r(p[j]);
            const bf8* bw = (const bf8*)(WaB + lr * 64 + kb * 32 + quad * 8);
            sc = __builtin_amdgcn_mfma_f32_16x16x32_bf16(a, *bw, sc, 0, 0, 0);
        }
        #pragma unroll
        for (int j = 0; j < 4; ++j) {
            int n = n0 + quad * 4 + j;
            if (lr < 8) s_src[n * 8 + lr] = sc[j];
            else        s_dst[n * 8 + (lr - 8)] = sc[j];
        }
    }
}

// ---- one-time CSR build (compact, exact) ----
__global__ void edge_count(const int* __restrict__ ei, const int* __restrict__ et,
                           int* __restrict__ counts, int* __restrict__ rank) {
    int e = blockIdx.x * 256 + threadIdx.x;
    int d = ei[EE + e], t = et[e];
    rank[e] = atomicAdd(&counts[d * 8 + t], 1);
}

__global__ void scan1(const int* __restrict__ counts, int* __restrict__ offs,
                      int* __restrict__ bsum) {
    __shared__ int s[256];
    int tid = threadIdx.x;
    int i = blockIdx.x * 256 + tid;
    int v = (i < NR) ? counts[i] : 0;
    s[tid] = v; __syncthreads();
    for (int d = 1; d < 256; d <<= 1) {
        int x = (tid >= d) ? s[tid - d] : 0;
        __syncthreads();
        s[tid] += x;
        __syncthreads();
    }
    if (i < NR) offs[i] = s[tid] - v;   // local (per-block) exclusive prefix
    if (tid == 255) bsum[blockIdx.x] = s[255];
}

__global__ void scan2(int* __restrict__ bsum) {   // 1024 threads, 2 chunks
    __shared__ int s[1024];
    int tid = threadIdx.x;
    int carry = 0;
    for (int c0 = 0; c0 < NB; c0 += 1024) {
        int i = c0 + tid;
        int v = (i < NB) ? bsum[i] : 0;
        s[tid] = v; __syncthreads();
        for (int d = 1; d < 1024; d <<= 1) {
            int x = (tid >= d) ? s[tid - d] : 0;
            __syncthreads();
            s[tid] += x;
            __syncthreads();
        }
        if (i < NB) bsum[i] = carry + s[tid] - v;
        int tot = s[1023];
        __syncthreads();
        carry += tot;
    }
}

// spack[slot] = {src, seg}; slot = offs[seg] + bsum[seg>>8] + rank
__global__ void edge_fill(const int* __restrict__ ei, const int* __restrict__ et,
                          const int* __restrict__ rank, const int* __restrict__ offs,
                          const int* __restrict__ bsum, u2* __restrict__ spack) {
    int e = blockIdx.x * 256 + threadIdx.x;
    int s = ei[e], d = ei[EE + e], t = et[e];
    int seg = d * 8 + t;
    int slot = offs[seg] + bsum[seg >> 8] + rank[e];
    spack[slot] = (u2){(unsigned)s, (unsigned)seg};
}

// weights -> bf16: WrB/WgB [r][kout][kd]; WaB [16][64]; WoB [kout][kd]
__global__ void cvt_w(const float* __restrict__ Wr, const float* __restrict__ Wg,
                      const float* __restrict__ Wa, const float* __restrict__ Wo,
                      unsigned short* __restrict__ WrB, unsigned short* __restrict__ WgB,
                      unsigned short* __restrict__ WaB, unsigned short* __restrict__ WoB) {
    int i = blockIdx.x * 256 + threadIdx.x;   // 32768 total
    WrB[i] = bf16r(Wr[i]);
    WgB[i] = bf16r(Wg[i]);
    if (i < 1024) {
        int row = i >> 6, k = i & 63;
        float v = (row < 8) ? Wa[row * 128 + k] : Wa[(row - 8) * 128 + 64 + k];
        WaB[i] = bf16r(v);
    }
    if (i < 4096) WoB[i] = bf16r(Wo[i]);
}

// slot-parallel softmax; epack[slot] = {src, ex}; per-type denom partials
// (no max subtraction: |score|<~8, fp32-safe; softmax ratio shift-invariant)
__global__ void edge_softmax2(const u2* __restrict__ spack,
                              const float* __restrict__ s_src, const float* __restrict__ s_dst,
                              const float* __restrict__ b_att,
                              u2* __restrict__ epack, float* __restrict__ dpart) {
    __shared__ float lsum[4][8];
    int tid = threadIdx.x;
    if (tid < 32) lsum[tid >> 3][tid & 7] = 0.f;
    __syncthreads();
    int slot = blockIdx.x * 256 + tid;     // EE % 256 == 0
    u2 sp = spack[slot];
    int src = (int)sp[0];
    int seg = (int)sp[1];
    int t = seg & 7;
    float sc = s_src[src * 8 + t] + s_dst[seg] + b_att[t];
    sc = (sc >= 0.f) ? sc : NEG_SLOPE * sc;
    float ex = __expf(sc);
    epack[slot] = (u2){(unsigned)src, __float_as_uint(ex)};
    atomicAdd(&lsum[tid >> 6][t], ex);
    __syncthreads();
    if (tid < 8) {
        float v = lsum[0][tid] + lsum[1][tid] + lsum[2][tid] + lsum[3][tid];
        atomicAdd(&dpart[(blockIdx.x & (DSPREAD - 1)) * 16 + tid], v);
    }
}

// one-block reduce: dpart (64 rows x 16, types 0..7) -> idn8 = 1/sum
__global__ void denom_reduce(const float* __restrict__ dpartL,
                             float* __restrict__ idn8L) {
    __shared__ float sb[256];
    int t = threadIdx.x;
    int rb = t >> 3, ty = t & 7;
    float v = dpartL[rb * 16 + ty] + dpartL[(rb + 32) * 16 + ty];
    sb[t] = v; __syncthreads();
    for (int st = 128; st >= 8; st >>= 1) {
        if (t < st) sb[t] += sb[t + st];
        __syncthreads();
    }
    if (t < 8) idn8L[t] = 1.f / sb[t];
}

// K1: barrier-free, LDS-free segment gather (r8-verified).
__global__ __launch_bounds__(256, 4) void gather_seg(
    const int* __restrict__ offs, const int* __restrict__ bsum,
    const u2* __restrict__ epack, const float* __restrict__ idn8L,
    const unsigned short* __restrict__ hbf_in,
    unsigned short* __restrict__ psG) {
    int tid = threadIdx.x;
    int segl = tid >> 1, half = tid & 1;
    int sidx = blockIdx.x * 128 + segl;      // global (node,r) segment id
    int lo = offs[sidx] + bsum[sidx >> 8];
    int nxt = sidx + 1;
    int hi = (nxt < NR) ? (offs[nxt] + bsum[nxt >> 8]) : EE;
    int r = segl & 7, gn = segl >> 3;

    // uniform-address scalar load of 8 inverse denoms; per-lane select
    f4 d0 = *(const f4*)(idn8L);
    f4 d1 = *(const f4*)(idn8L + 4);
    float i01 = (r & 1) ? d0[1] : d0[0];
    float i23 = (r & 1) ? d0[3] : d0[2];
    float i45 = (r & 1) ? d1[1] : d1[0];
    float i67 = (r & 1) ? d1[3] : d1[2];
    float i03 = (r & 2) ? i23 : i01;
    float i47 = (r & 2) ? i67 : i45;
    float idn = (r & 4) ? i47 : i03;

    f2 acc[16];
    #pragma unroll
    for (int i = 0; i < 16; ++i) acc[i] = (f2){0.f, 0.f};

    for (int s = lo; s < hi; s += 4) {
        int i1 = (s + 1 < hi) ? s + 1 : s;
        int i2 = (s + 2 < hi) ? s + 2 : s;
        int i3 = (s + 3 < hi) ? s + 3 : s;
        u2 pk0 = epack[s], pk1 = epack[i1], pk2 = epack[i2], pk3 = epack[i3];
        float a0 = __uint_as_float(pk0[1]);
        float a1 = (s + 1 < hi) ? __uint_as_float(pk1[1]) : 0.f;
        float a2 = (s + 2 < hi) ? __uint_as_float(pk2[1]) : 0.f;
        float a3 = (s + 3 < hi) ? __uint_as_float(pk3[1]) : 0.f;
        const u4* hp0 = (const u4*)(hbf_in + ((size_t)(int)pk0[0] << 6) + half * 32);
        const u4* hp1 = (const u4*)(hbf_in + ((size_t)(int)pk1[0] << 6) + half * 32);
        const u4* hp2 = (const u4*)(hbf_in + ((size_t)(int)pk2[0] << 6) + half * 32);
        const u4* hp3 = (const u4*)(hbf_in + ((size_t)(int)pk3[0] << 6) + half * 32);
        #pragma unroll
        for (int q = 0; q < 4; ++q) {
            u4 v0 = hp0[q], v1 = hp1[q], v2 = hp2[q], v3 = hp3[q];
            #pragma unroll
            for (int k = 0; k < 4; ++k) {
                f2 w0, w1, w2, w3;
                w0[0] = __uint_as_float(v0[k] << 16);
                w0[1] = __uint_as_float(v0[k] & 0xffff0000u);
                w1[0] = __uint_as_float(v1[k] << 16);
                w1[1] = __uint_as_float(v1[k] & 0xffff0000u);
                w2[0] = __uint_as_float(v2[k] << 16);
                w2[1] = __uint_as_float(v2[k] & 0xffff0000u);
                w3[0] = __uint_as_float(v3[k] << 16);
                w3[1] = __uint_as_float(v3[k] & 0xffff0000u);
                acc[q * 4 + k] += (f2){a0, a0} * w0;
                acc[q * 4 + k] += (f2){a1, a1} * w1;
                acc[q * 4 + k] += (f2){a2, a2} * w2;
                acc[q * 4 + k] += (f2){a3, a3} * w3;
            }
        }
    }

    // swizzled pack + store: chunk index (half*4+q) ^ (gn&7) within the
    // (gn,r) 128B sub-row; combine reads LDS with the same XOR.
    unsigned short* base = psG + ((size_t)blockIdx.x << 13) + gn * 512 + r * 64;
    #pragma unroll
    for (int q = 0; q < 4; ++q) {
        us8 o;
        #pragma unroll
        for (int k = 0; k < 4; ++k) {
            o[2 * k]     = bf16r(acc[q * 4 + k][0] * idn);
            o[2 * k + 1] = bf16r(acc[q * 4 + k][1] * idn);
        }
        int c2 = (half * 4 + q) ^ (gn & 7);
        *(us8*)(base + c2 * 8) = o;
    }
}

// stage one 16-node group (psG 16KB linear + hbuf 4KB src-swizzled) into
// buffer b. 5 global_load_lds per wave => vmcnt accounting unit = 5.
#define STAGE_GRP(b, g) do { \
    int n0s_ = nb0 + (g) * 16; \
    const char* ps_src_ = (const char*)psG + (size_t)n0s_ * 1024; \
    _Pragma("unroll") \
    for (int i_ = 0; i_ < 4; ++i_) { \
        unsigned off_ = i_ * 4096 + w * 1024; \
        stage16(ps_src_ + off_ + lane * 16, (char*)psL[b] + off_); \
    } \
    unsigned a_ = (unsigned)(w * 1024 + lane * 16); \
    unsigned sa_ = a_ ^ (((a_ >> 8) & 7u) << 4); \
    stage16((const char*)(hbuf + (size_t)n0s_ * 64) + sa_, (char*)hsL[b] + a_); \
} while (0)

// K2: dense combine (r8-verified, 411.9us total) — 80-node blocks (625),
// 5 groups, double-buffered staging. Per group: issue stage(g+1), counted
// s_waitcnt vmcnt(5) + RAW s_barrier (the only hand-rolled sync;
// __syncthreads would drain vmcnt(0) and kill the overlap), MFMA phases run
// under stage(g+1)'s latency. W fragments: 32 volatile-asm loads ONCE per
// block (5x reuse). In-order vmcnt retirement makes the counted wait
// conservative-correct. All remaining barriers = __syncthreads.
template<bool EMIT, bool OUT>
__global__ __launch_bounds__(256, 2) void combine_dense(
    const float* __restrict__ hbuf, const unsigned short* __restrict__ psG,
    const unsigned short* __restrict__ WrB, const unsigned short* __restrict__ WgB,
    const unsigned short* __restrict__ WaB, const unsigned short* __restrict__ WoB,
    const float* __restrict__ b_gate, const float* __restrict__ gamma,
    const float* __restrict__ beta, float* __restrict__ hout,
    unsigned short* __restrict__ hbf_out, float* __restrict__ ssrc_out,
    float* __restrict__ sdst_out, float* __restrict__ outp,
    const float* __restrict__ b_out) {
    __shared__ unsigned short psL[2][8192];   // 2 x 16KB a_p tiles / fp32 t,o scratch
    __shared__ float hsL[2][1024];            // 2 x 4KB h tiles (swizzled)
    int tid = threadIdx.x;
    int nb0 = blockIdx.x * NPB;
    int w = tid >> 6, lane = tid & 63;
    int quad = lane >> 4, lr = lane & 15;
    int tn = w;

    STAGE_GRP(0, 0);

    // W fragments once per block (volatile asm: resident for all 5 groups)
    unsigned rowb = (unsigned)((tn * 16 + lr) * 128 + quad * 16);
    u4 wr[8][2], wg[8][2];
    #pragma unroll
    for (int r = 0; r < 8; ++r) {
        WLOADP(wr[r][0], wr[r][1], WrB, rowb + (unsigned)r * 8192u);
        WLOADP(wg[r][0], wg[r][1], WgB, rowb + (unsigned)r * 8192u);
    }
    float bgv[8];
    #pragma unroll
    for (int r = 0; r < 8; ++r) bgv[r] = b_gate[r * 64 + tn * 16 + lr];
    f4 gmv = *(const f4*)(gamma + (tid & 15) * 4);
    f4 btv = *(const f4*)(beta + (tid & 15) * 4);

    for (int g = 0; g < NGRP; ++g) {
        int cb = g & 1;
        int n0 = nb0 + g * 16;
        if (g + 1 < NGRP) {
            STAGE_GRP(cb ^ 1, g + 1);
            // retire everything older than the newest 5 (= stage g+1):
            // stage(g) + W + any compiler vmem guaranteed complete.
            asm volatile("s_waitcnt vmcnt(5)" ::: "memory");
        } else {
            asm volatile("s_waitcnt vmcnt(0)" ::: "memory");
        }
        __builtin_amdgcn_sched_barrier(0);
        __builtin_amdgcn_s_barrier();      // stage(g) visible to all waves

        // A_h fragments from hsL[cb] (swizzled chunks)
        bf8 a_h[2];
        #pragma unroll
        for (int kb = 0; kb < 2; ++kb) {
            unsigned c0 = (unsigned)(kb * 8 + quad * 2)     ^ (unsigned)(lr & 7);
            unsigned c1 = (unsigned)(kb * 8 + quad * 2 + 1) ^ (unsigned)(lr & 7);
            f4 p0 = *(const f4*)((const char*)hsL[cb] + lr * 256 + c0 * 16);
            f4 p1 = *(const f4*)((const char*)hsL[cb] + lr * 256 + c1 * 16);
            bf8 a;
            #pragma unroll
            for (int j = 0; j < 4; ++j) a[j] = (short)bf16r(p0[j]);
            #pragma unroll
            for (int j = 0; j < 4; ++j) a[4 + j] = (short)bf16r(p1[j]);
            a_h[kb] = a;
        }

        // 8 relation MFMA phases (W from regs; a_p from psL[cb]) —
        // stage(g+1) flies underneath this.
        f4 acc = (f4){0.f, 0.f, 0.f, 0.f};
        #pragma unroll
        for (int r = 0; r < 8; ++r) {
            bf8 a_p[2];
            #pragma unroll
            for (int kb = 0; kb < 2; ++kb) {
                unsigned c = (unsigned)(kb * 4 + quad) ^ (unsigned)(lr & 7);
                a_p[kb] = *(const bf8*)((const char*)psL[cb] + lr * 1024 + r * 128 + c * 16);
            }
            f4 aggc = (f4){0.f, 0.f, 0.f, 0.f};
            f4 gacc = (f4){0.f, 0.f, 0.f, 0.f};
            aggc = __builtin_amdgcn_mfma_f32_16x16x32_bf16(a_p[0], asbf8(wr[r][0]), aggc, 0, 0, 0);
            gacc = __builtin_amdgcn_mfma_f32_16x16x32_bf16(a_h[0], asbf8(wg[r][0]), gacc, 0, 0, 0);
            aggc = __builtin_amdgcn_mfma_f32_16x16x32_bf16(a_p[1], asbf8(wr[r][1]), aggc, 0, 0, 0);
            gacc = __builtin_amdgcn_mfma_f32_16x16x32_bf16(a_h[1], asbf8(wg[r][1]), gacc, 0, 0, 0);
            #pragma unroll
            for (int j = 0; j < 4; ++j) {
                float gt = 1.f / (1.f + __expf(-(gacc[j] + bgv[r])));
                acc[j] += gt * aggc[j];
            }
        }
        __syncthreads();   // all waves done reading psL[cb] -> reuse as fp32

        float* ps_f = (float*)psL[cb];
        // t = h + acc/8 into ps_f rows 0..15; residual from swizzled hsL[cb]
        #pragma unroll
        for (int j = 0; j < 4; ++j) {
            int row = quad * 4 + j;
            int col = tn * 16 + lr;
            unsigned y = (unsigned)(row * 256 + col * 4);
            float hres = *(const float*)((const char*)hsL[cb] + (y ^ (((unsigned)(row & 7)) << 4)));
            ps_f[row * LDH + col] = hres + acc[j] * 0.125f;
        }
        __syncthreads();

        // LN + ReLU; o-tile into ps_f[OTB..) (disjoint region)
        {
            int row = tid >> 4, c = tid & 15;
            int n = n0 + row;
            f4 tv = *(const f4*)&ps_f[row * LDH + c * 4];
            float s1 = tv[0] + tv[1] + tv[2] + tv[3];
            float s2 = tv[0]*tv[0] + tv[1]*tv[1] + tv[2]*tv[2] + tv[3]*tv[3];
            #pragma unroll
            for (int off = 1; off <= 8; off <<= 1) {
                s1 += __shfl_xor(s1, off, 64);
                s2 += __shfl_xor(s2, off, 64);
            }
            float mu = s1 * (1.f / 64.f);
            float var = s2 * (1.f / 64.f) - mu * mu;
            float rs = rsqrtf(var + LN_EPS);
            f4 ov;
            #pragma unroll
            for (int j = 0; j < 4; ++j)
                ov[j] = fmaxf((tv[j] - mu) * rs * gmv[j] + btv[j], 0.f);
            if (!OUT)
                *(f4*)(hout + (size_t)n * 64 + c * 4) = ov;
            *(f4*)&ps_f[OTB + row * LDH + c * 4] = ov;
            if (EMIT) {
                u2 u;
                u[0] = (unsigned)bf16r(ov[0]) | ((unsigned)bf16r(ov[1]) << 16);
                u[1] = (unsigned)bf16r(ov[2]) | ((unsigned)bf16r(ov[3]) << 16);
                *(u2*)(hbf_out + (size_t)n * 64 + c * 4) = u;
            }
        }

        if (EMIT) {
            __syncthreads();
            if (w == 0) {   // next-layer attention pre-scores
                f4 sc = (f4){0.f, 0.f, 0.f, 0.f};
                #pragma unroll
                for (int kb = 0; kb < 2; ++kb) {
                    const float* p = &ps_f[OTB + lr * LDH + kb * 32 + quad * 8];
                    bf8 a;
                    #pragma unroll
                    for (int j = 0; j < 8; ++j) a[j] = (short)bf16r(p[j]);
                    const bf8* bw = (const bf8*)(WaB + lr * 64 + kb * 32 + quad * 8);
                    sc = __builtin_amdgcn_mfma_f32_16x16x32_bf16(a, *bw, sc, 0, 0, 0);
                }
                #pragma unroll
                for (int j = 0; j < 4; ++j) {
                    int n = n0 + quad * 4 + j;
                    if (lr < 8) ssrc_out[n * 8 + lr] = sc[j];
                    else        sdst_out[n * 8 + (lr - 8)] = sc[j];
                }
            }
        }

        if (OUT) {
            __syncthreads();
            f4 oc = (f4){0.f, 0.f, 0.f, 0.f};
            #pragma unroll
            for (int kb = 0; kb < 2; ++kb) {
                const float* p = &ps_f[OTB + lr * LDH + kb * 32 + quad * 8];
                bf8 a;
                #pragma unroll
                for (int j = 0; j < 8; ++j) a[j] = (short)bf16r(p[j]);
                const bf8* bw = (const bf8*)(WoB + ((tn * 16 + lr) * 64 + kb * 32 + quad * 8));
                oc = __builtin_amdgcn_mfma_f32_16x16x32_bf16(a, *bw, oc, 0, 0, 0);
            }
            float bo = b_out[tn * 16 + lr];
            #pragma unroll
            for (int j = 0; j < 4; ++j)
                outp[(size_t)(n0 + quad * 4 + j) * 64 + tn * 16 + lr] = oc[j] + bo;
        }
        __syncthreads();   // epilogue done: buffer reusable by stage(g+2)
    }
}

extern "C" void kernel_launch(void* const* d_in, const int* in_sizes, int n_in,
                              void* d_out, int out_size, void* d_ws, size_t ws_size,
                              hipStream_t stream) {
    const float* x      = (const float*)d_in[0];
    const int*   ei     = (const int*)d_in[1];
    const int*   et     = (const int*)d_in[2];
    const float* W_in   = (const float*)d_in[3];
    const float* b_in   = (const float*)d_in[4];
    const float* W_rel  = (const float*)d_in[5];
    const float* W_gate = (const float*)d_in[6];
    const float* b_gate = (const float*)d_in[7];
    const float* W_att  = (const float*)d_in[8];
    const float* b_att  = (const float*)d_in[9];
    const float* ln_g   = (const float*)d_in[10];
    const float* ln_b   = (const float*)d_in[11];
    const float* W_out  = (const float*)d_in[12];
    const float* b_out  = (const float*)d_in[13];
    float* out = (float*)d_out;

    float* h0 = (float*)d_out;          // ping-pong A (scratch until final layer)

    char* ws = (char*)d_ws;
    float* h1 = (float*)ws;                     ws += (size_t)NN * 64 * 4;
    unsigned short* hbfA = (unsigned short*)ws; ws += (size_t)NN * 64 * 2;
    unsigned short* hbfB = (unsigned short*)ws; ws += (size_t)NN * 64 * 2;
    float* s_src = (float*)ws;                  ws += (size_t)NN * 8 * 4;
    float* s_dst = (float*)ws;                  ws += (size_t)NN * 8 * 4;
    unsigned short* WrB = (unsigned short*)ws;  ws += (size_t)RR * 64 * 64 * 2;
    unsigned short* WgB = (unsigned short*)ws;  ws += (size_t)RR * 64 * 64 * 2;
    unsigned short* WaB = (unsigned short*)ws;  ws += 2048;
    unsigned short* WoB = (unsigned short*)ws;  ws += 8192;
    // contiguous zero region: counts + 3 per-layer dpart regions
    int* counts = (int*)ws;                     ws += (size_t)NR * 4;
    float* dpart = (float*)ws;                  ws += 3 * DSPREAD * 16 * 4;
    float* idn8G = (float*)ws;                  ws += 3 * 16 * 4;   // 8 used/layer
    int* offs = (int*)ws;                       ws += (size_t)NR * 4;
    int* bsum = (int*)ws;                       ws += 6400;
    int* rank = (int*)ws;                       ws += (size_t)EE * 4;
    u2* spack = (u2*)ws;                        ws += (size_t)EE * 8;
    u2* epack = (u2*)ws;                        ws += (size_t)EE * 8;
    unsigned short* psG = (unsigned short*)ws;  ws += (size_t)NR * 64 * 2;  // 51.2MB

    hipMemsetAsync(counts, 0, (size_t)NR * 4 + 3 * DSPREAD * 16 * 4, stream);
    cvt_w<<<128, 256, 0, stream>>>(W_rel, W_gate, W_att, W_out, WrB, WgB, WaB, WoB);
    edge_count<<<EE / 256, 256, 0, stream>>>(ei, et, counts, rank);
    scan1<<<NB, 256, 0, stream>>>(counts, offs, bsum);
    scan2<<<1, 1024, 0, stream>>>(bsum);
    edge_fill<<<EE / 256, 256, 0, stream>>>(ei, et, rank, offs, bsum, spack);
    proj_in<<<NN / 16, 256, 0, stream>>>(x, W_in, b_in, WaB, h0, hbfA, s_src, s_dst);

    const int tiles16 = NN / 16;    // 3125 (gather grid)
    const int tiles80 = NN / NPB;   // 625 (combine grid)
    float* hA = h0;  float* hB = h1;
    unsigned short* bfA = hbfA;  unsigned short* bfB = hbfB;
    for (int layer = 0; layer < LL; ++layer) {
        float* dpl = dpart + (size_t)layer * DSPREAD * 16;
        float* idn = idn8G + (size_t)layer * 16;
        edge_softmax2<<<EE / 256, 256, 0, stream>>>(spack, s_src, s_dst, b_att,
                                                    epack, dpl);
        denom_reduce<<<1, 256, 0, stream>>>(dpl, idn);
        gather_seg<<<tiles16, 256, 0, stream>>>(offs, bsum, epack, idn, bfA, psG);
        if (layer < LL - 1) {
            combine_dense<true, false><<<tiles80, 256, 0, stream>>>(
                hA, psG, WrB, WgB, WaB, WoB, b_gate,
                ln_g + layer * 64, ln_b + layer * 64,
                hB, bfB, s_src, s_dst, out, b_out);
        } else {
            combine_dense<false, true><<<tiles80, 256, 0, stream>>>(
                hA, psG, WrB, WgB, WaB, WoB, b_gate,
                ln_g + layer * 64, ln_b + layer * 64,
                hB, bfB, s_src, s_dst, out, b_out);
        }
        float* tf = hA; hA = hB; hB = tf;
        unsigned short* tb = bfA; bfA = bfB; bfB = tb;
    }
}

// Round 13
// 389.023 us; speedup vs baseline: 1.1746x; 1.0673x over previous
//
#include <hip/hip_runtime.h>
#include <math.h>

#define NN 50000
#define EE 800000
#define HH 64
#define RR 8
#define LL 3
#define NR (NN * RR)            // 400000 segments
#define NB ((NR + 255) / 256)   // 1563 scan blocks
#define LN_EPS 1e-5f
#define NEG_SLOPE 0.2f
#define LDH 68                  // fp32 row stride for t/o tiles in reused psL
#define OTB (16 * LDH)          // o-tile base (floats) inside ps_f
#define DSPREAD 64              // denom partial rows (distinct cachelines)
#define NPB 80                  // nodes per combine block (50000 = 625*80)
#define NGRP 5                  // 16-node groups per combine block

typedef __attribute__((ext_vector_type(8))) short bf8;
typedef __attribute__((ext_vector_type(4))) float f4;
typedef __attribute__((ext_vector_type(2))) float f2;
typedef __attribute__((ext_vector_type(8))) unsigned short us8;
typedef __attribute__((ext_vector_type(2))) unsigned int u2;
typedef __attribute__((ext_vector_type(4))) unsigned int u4;

// inline-asm W-fragment pair load: volatile => cannot be sunk/rematerialized
// (the r3/r4/r5 failure mode). Loaded ONCE per block, reused across 5 groups.
// Landing guarantee: the first counted s_waitcnt in the group loop retires
// these before any use (r8-verified correct).
#define WLOADP(d0, d1, sbase, vbyte) \
    asm volatile("global_load_dwordx4 %0, %2, %3 offset:0\n\t" \
                 "global_load_dwordx4 %1, %2, %3 offset:64" \
        : "=&v"(d0), "=&v"(d1) : "v"(vbyte), "s"(sbase) : "memory")

__device__ __forceinline__ unsigned short bf16r(float f) {
    unsigned u = __float_as_uint(f);
    unsigned r = u + 0x7fffu + ((u >> 16) & 1u);
    return (unsigned short)(r >> 16);
}
__device__ __forceinline__ float bf2f(unsigned short u) {
    return __uint_as_float(((unsigned)u) << 16);
}
__device__ __forceinline__ bf8 asbf8(u4 v) {
    union { u4 a; bf8 b; } c; c.a = v; return c.b;
}
// fire-and-forget 16B global->LDS; completion via vmcnt accounting.
__device__ __forceinline__ void stage16(const void* g, void* l) {
    __builtin_amdgcn_global_load_lds(
        (const __attribute__((address_space(1))) void*)g,
        (__attribute__((address_space(3))) void*)l, 16, 0, 0);
}

// 16-node blocks: h = relu(x @ W_in^T + b_in) in fp32 via LDS;
// emit bf16 gather mirror; wave 0 computes s_src/s_dst via 2 MFMAs (WaB).
__global__ __launch_bounds__(256) void proj_in(
    const float* __restrict__ x, const float* __restrict__ W,
    const float* __restrict__ bias, const unsigned short* __restrict__ WaB,
    float* __restrict__ h, unsigned short* __restrict__ hbf,
    float* __restrict__ s_src, float* __restrict__ s_dst) {
    __shared__ float WT[64 * LDH];     // WT[i][k] = W[k][i]
    __shared__ float xs[16 * LDH];
    __shared__ float hs[16 * LDH];
    int tid = threadIdx.x;
    int n0 = blockIdx.x * 16;          // NN % 16 == 0
    #pragma unroll
    for (int s = 0; s < 16; ++s) {
        int idx = tid + 256 * s;
        int k = idx >> 6, i = idx & 63;
        WT[i * LDH + k] = W[idx];
    }
    int row = tid >> 4, cg = tid & 15;
    {
        f4 v = ((const f4*)x)[(size_t)(n0 + row) * 16 + cg];
        *(f4*)&xs[row * LDH + cg * 4] = v;
    }
    __syncthreads();
    f4 acc;
    {
        f4 b = *(const f4*)(bias + cg * 4);
        acc = b;
        #pragma unroll
        for (int i = 0; i < 64; ++i) {
            float xv = xs[row * LDH + i];
            f4 wt = *(const f4*)&WT[i * LDH + cg * 4];
            acc[0] += xv * wt[0];
            acc[1] += xv * wt[1];
            acc[2] += xv * wt[2];
            acc[3] += xv * wt[3];
        }
        #pragma unroll
        for (int j = 0; j < 4; ++j) acc[j] = fmaxf(acc[j], 0.f);
        int n = n0 + row;
        *(f4*)(h + (size_t)n * 64 + cg * 4) = acc;
        u2 u;
        u[0] = (unsigned)bf16r(acc[0]) | ((unsigned)bf16r(acc[1]) << 16);
        u[1] = (unsigned)bf16r(acc[2]) | ((unsigned)bf16r(acc[3]) << 16);
        *(u2*)(hbf + (size_t)n * 64 + cg * 4) = u;
        *(f4*)&hs[row * LDH + cg * 4] = acc;
    }
    __syncthreads();
    if (tid < 64) {      // wave 0: attention pre-scores via MFMA
        int lane = tid;
        int quad = lane >> 4, lr = lane & 15;
        f4 sc = (f4){0.f, 0.f, 0.f, 0.f};
        #pragma unroll
        for (int kb = 0; kb < 2; ++kb) {
            const float* p = &hs[lr * LDH + kb * 32 + quad * 8];
            bf8 a;
            #pragma unroll
            for (int j = 0; j < 8; ++j) a[j] = (short)bf16r(p[j]);
            const bf8* bw = (const bf8*)(WaB + lr * 64 + kb * 32 + quad * 8);
            sc = __builtin_amdgcn_mfma_f32_16x16x32_bf16(a, *bw, sc, 0, 0, 0);
        }
        #pragma unroll
        for (int j = 0; j < 4; ++j) {
            int n = n0 + quad * 4 + j;
            if (lr < 8) s_src[n * 8 + lr] = sc[j];
            else        s_dst[n * 8 + (lr - 8)] = sc[j];
        }
    }
}

// ---- one-time CSR build (compact, exact) ----
__global__ void edge_count(const int* __restrict__ ei, const int* __restrict__ et,
                           int* __restrict__ counts, int* __restrict__ rank) {
    int e = blockIdx.x * 256 + threadIdx.x;
    int d = ei[EE + e], t = et[e];
    rank[e] = atomicAdd(&counts[d * 8 + t], 1);
}

__global__ void scan1(const int* __restrict__ counts, int* __restrict__ offs,
                      int* __restrict__ bsum) {
    __shared__ int s[256];
    int tid = threadIdx.x;
    int i = blockIdx.x * 256 + tid;
    int v = (i < NR) ? counts[i] : 0;
    s[tid] = v; __syncthreads();
    for (int d = 1; d < 256; d <<= 1) {
        int x = (tid >= d) ? s[tid - d] : 0;
        __syncthreads();
        s[tid] += x;
        __syncthreads();
    }
    if (i < NR) offs[i] = s[tid] - v;   // local (per-block) exclusive prefix
    if (tid == 255) bsum[blockIdx.x] = s[255];
}

__global__ void scan2(int* __restrict__ bsum) {   // 1024 threads, 2 chunks
    __shared__ int s[1024];
    int tid = threadIdx.x;
    int carry = 0;
    for (int c0 = 0; c0 < NB; c0 += 1024) {
        int i = c0 + tid;
        int v = (i < NB) ? bsum[i] : 0;
        s[tid] = v; __syncthreads();
        for (int d = 1; d < 1024; d <<= 1) {
            int x = (tid >= d) ? s[tid - d] : 0;
            __syncthreads();
            s[tid] += x;
            __syncthreads();
        }
        if (i < NB) bsum[i] = carry + s[tid] - v;
        int tot = s[1023];
        __syncthreads();
        carry += tot;
    }
}

// spack[slot] = {src, seg}; slot = offs[seg] + bsum[seg>>8] + rank
__global__ void edge_fill(const int* __restrict__ ei, const int* __restrict__ et,
                          const int* __restrict__ rank, const int* __restrict__ offs,
                          const int* __restrict__ bsum, u2* __restrict__ spack) {
    int e = blockIdx.x * 256 + threadIdx.x;
    int s = ei[e], d = ei[EE + e], t = et[e];
    int seg = d * 8 + t;
    int slot = offs[seg] + bsum[seg >> 8] + rank[e];
    spack[slot] = (u2){(unsigned)s, (unsigned)seg};
}

// weights -> bf16: WrB/WgB [r][kout][kd]; WaB [16][64]; WoB [kout][kd]
__global__ void cvt_w(const float* __restrict__ Wr, const float* __restrict__ Wg,
                      const float* __restrict__ Wa, const float* __restrict__ Wo,
                      unsigned short* __restrict__ WrB, unsigned short* __restrict__ WgB,
                      unsigned short* __restrict__ WaB, unsigned short* __restrict__ WoB) {
    int i = blockIdx.x * 256 + threadIdx.x;   // 32768 total
    WrB[i] = bf16r(Wr[i]);
    WgB[i] = bf16r(Wg[i]);
    if (i < 1024) {
        int row = i >> 6, k = i & 63;
        float v = (row < 8) ? Wa[row * 128 + k] : Wa[(row - 8) * 128 + 64 + k];
        WaB[i] = bf16r(v);
    }
    if (i < 4096) WoB[i] = bf16r(Wo[i]);
}

// slot-parallel softmax; epack[slot] = {src, ex}; per-type denom partials
// (no max subtraction: |score|<~8, fp32-safe; softmax ratio shift-invariant)
__global__ void edge_softmax2(const u2* __restrict__ spack,
                              const float* __restrict__ s_src, const float* __restrict__ s_dst,
                              const float* __restrict__ b_att,
                              u2* __restrict__ epack, float* __restrict__ dpart) {
    __shared__ float lsum[4][8];
    int tid = threadIdx.x;
    if (tid < 32) lsum[tid >> 3][tid & 7] = 0.f;
    __syncthreads();
    int slot = blockIdx.x * 256 + tid;     // EE % 256 == 0
    u2 sp = spack[slot];
    int src = (int)sp[0];
    int seg = (int)sp[1];
    int t = seg & 7;
    float sc = s_src[src * 8 + t] + s_dst[seg] + b_att[t];
    sc = (sc >= 0.f) ? sc : NEG_SLOPE * sc;
    float ex = __expf(sc);
    epack[slot] = (u2){(unsigned)src, __float_as_uint(ex)};
    atomicAdd(&lsum[tid >> 6][t], ex);
    __syncthreads();
    if (tid < 8) {
        float v = lsum[0][tid] + lsum[1][tid] + lsum[2][tid] + lsum[3][tid];
        atomicAdd(&dpart[(blockIdx.x & (DSPREAD - 1)) * 16 + tid], v);
    }
}

// one-block reduce: dpart (64 rows x 16, types 0..7) -> idn8 = 1/sum
__global__ void denom_reduce(const float* __restrict__ dpartL,
                             float* __restrict__ idn8L) {
    __shared__ float sb[256];
    int t = threadIdx.x;
    int rb = t >> 3, ty = t & 7;
    float v = dpartL[rb * 16 + ty] + dpartL[(rb + 32) * 16 + ty];
    sb[t] = v; __syncthreads();
    for (int st = 128; st >= 8; st >>= 1) {
        if (t < st) sb[t] += sb[t + st];
        __syncthreads();
    }
    if (t < 8) idn8L[t] = 1.f / sb[t];
}

// K1: barrier-free, LDS-free segment gather — QUARTER-SPLIT (r13):
// thread = (segment, 16-col quarter). Halves per-thread footprint vs the
// half-split (acc 32->16 floats, 4->2 u4 loads/edge) => fits (256,6)'s
// 85-VGPR cap => 6 blocks/CU latency hiding (was 4). Block = 64 segments
// = 8 nodes; grid 6250. psG global layout node-linear, byte-identical to
// r12 (combine untouched). epack read 4x redundant (L2-resident, cheap).
__global__ __launch_bounds__(256, 6) void gather_seg(
    const int* __restrict__ offs, const int* __restrict__ bsum,
    const u2* __restrict__ epack, const float* __restrict__ idn8L,
    const unsigned short* __restrict__ hbf_in,
    unsigned short* __restrict__ psG) {
    int tid = threadIdx.x;
    int segl = tid >> 2, qt = tid & 3;
    int sidx = blockIdx.x * 64 + segl;       // global (node,r) segment id
    int lo = offs[sidx] + bsum[sidx >> 8];
    int nxt = sidx + 1;
    int hi = (nxt < NR) ? (offs[nxt] + bsum[nxt >> 8]) : EE;
    int r = segl & 7, gn = segl >> 3;        // gn in 0..7 (8 nodes/block)

    // uniform-address scalar load of 8 inverse denoms; per-lane select
    f4 d0 = *(const f4*)(idn8L);
    f4 d1 = *(const f4*)(idn8L + 4);
    float i01 = (r & 1) ? d0[1] : d0[0];
    float i23 = (r & 1) ? d0[3] : d0[2];
    float i45 = (r & 1) ? d1[1] : d1[0];
    float i67 = (r & 1) ? d1[3] : d1[2];
    float i03 = (r & 2) ? i23 : i01;
    float i47 = (r & 2) ? i67 : i45;
    float idn = (r & 4) ? i47 : i03;

    f2 acc[8];
    #pragma unroll
    for (int i = 0; i < 8; ++i) acc[i] = (f2){0.f, 0.f};

    for (int s = lo; s < hi; s += 4) {
        int i1 = (s + 1 < hi) ? s + 1 : s;
        int i2 = (s + 2 < hi) ? s + 2 : s;
        int i3 = (s + 3 < hi) ? s + 3 : s;
        u2 pk0 = epack[s], pk1 = epack[i1], pk2 = epack[i2], pk3 = epack[i3];
        float a0 = __uint_as_float(pk0[1]);
        float a1 = (s + 1 < hi) ? __uint_as_float(pk1[1]) : 0.f;
        float a2 = (s + 2 < hi) ? __uint_as_float(pk2[1]) : 0.f;
        float a3 = (s + 3 < hi) ? __uint_as_float(pk3[1]) : 0.f;
        const u4* hp0 = (const u4*)(hbf_in + ((size_t)(int)pk0[0] << 6) + qt * 16);
        const u4* hp1 = (const u4*)(hbf_in + ((size_t)(int)pk1[0] << 6) + qt * 16);
        const u4* hp2 = (const u4*)(hbf_in + ((size_t)(int)pk2[0] << 6) + qt * 16);
        const u4* hp3 = (const u4*)(hbf_in + ((size_t)(int)pk3[0] << 6) + qt * 16);
        #pragma unroll
        for (int q = 0; q < 2; ++q) {
            u4 v0 = hp0[q], v1 = hp1[q], v2 = hp2[q], v3 = hp3[q];
            #pragma unroll
            for (int k = 0; k < 4; ++k) {
                f2 w0, w1, w2, w3;
                w0[0] = __uint_as_float(v0[k] << 16);
                w0[1] = __uint_as_float(v0[k] & 0xffff0000u);
                w1[0] = __uint_as_float(v1[k] << 16);
                w1[1] = __uint_as_float(v1[k] & 0xffff0000u);
                w2[0] = __uint_as_float(v2[k] << 16);
                w2[1] = __uint_as_float(v2[k] & 0xffff0000u);
                w3[0] = __uint_as_float(v3[k] << 16);
                w3[1] = __uint_as_float(v3[k] & 0xffff0000u);
                acc[q * 4 + k] += (f2){a0, a0} * w0;
                acc[q * 4 + k] += (f2){a1, a1} * w1;
                acc[q * 4 + k] += (f2){a2, a2} * w2;
                acc[q * 4 + k] += (f2){a3, a3} * w3;
            }
        }
    }

    // swizzled pack + store: chunk index (qt*2+q) ^ (gn&7) within the
    // (gn,r) 128B sub-row; combine reads LDS with the same XOR.
    // node = blockIdx.x*8 + gn  =>  address node*512 + r*64 (node-linear,
    // identical to r12's image).
    unsigned short* base = psG + ((size_t)blockIdx.x << 12) + gn * 512 + r * 64;
    #pragma unroll
    for (int q = 0; q < 2; ++q) {
        us8 o;
        #pragma unroll
        for (int k = 0; k < 4; ++k) {
            o[2 * k]     = bf16r(acc[q * 4 + k][0] * idn);
            o[2 * k + 1] = bf16r(acc[q * 4 + k][1] * idn);
        }
        int c2 = (qt * 2 + q) ^ (gn & 7);
        *(us8*)(base + c2 * 8) = o;
    }
}

// stage one 16-node group (psG 16KB linear + hbuf 4KB src-swizzled) into
// buffer b. 5 global_load_lds per wave => vmcnt accounting unit = 5.
#define STAGE_GRP(b, g) do { \
    int n0s_ = nb0 + (g) * 16; \
    const char* ps_src_ = (const char*)psG + (size_t)n0s_ * 1024; \
    _Pragma("unroll") \
    for (int i_ = 0; i_ < 4; ++i_) { \
        unsigned off_ = i_ * 4096 + w * 1024; \
        stage16(ps_src_ + off_ + lane * 16, (char*)psL[b] + off_); \
    } \
    unsigned a_ = (unsigned)(w * 1024 + lane * 16); \
    unsigned sa_ = a_ ^ (((a_ >> 8) & 7u) << 4); \
    stage16((const char*)(hbuf + (size_t)n0s_ * 64) + sa_, (char*)hsL[b] + a_); \
} while (0)

// K2: dense combine (r8-verified) — 80-node blocks (625), 5 groups,
// double-buffered staging, counted s_waitcnt vmcnt(5) + RAW s_barrier,
// W fragments resident once per block. Unchanged this round.
template<bool EMIT, bool OUT>
__global__ __launch_bounds__(256, 2) void combine_dense(
    const float* __restrict__ hbuf, const unsigned short* __restrict__ psG,
    const unsigned short* __restrict__ WrB, const unsigned short* __restrict__ WgB,
    const unsigned short* __restrict__ WaB, const unsigned short* __restrict__ WoB,
    const float* __restrict__ b_gate, const float* __restrict__ gamma,
    const float* __restrict__ beta, float* __restrict__ hout,
    unsigned short* __restrict__ hbf_out, float* __restrict__ ssrc_out,
    float* __restrict__ sdst_out, float* __restrict__ outp,
    const float* __restrict__ b_out) {
    __shared__ unsigned short psL[2][8192];   // 2 x 16KB a_p tiles / fp32 t,o scratch
    __shared__ float hsL[2][1024];            // 2 x 4KB h tiles (swizzled)
    int tid = threadIdx.x;
    int nb0 = blockIdx.x * NPB;
    int w = tid >> 6, lane = tid & 63;
    int quad = lane >> 4, lr = lane & 15;
    int tn = w;

    STAGE_GRP(0, 0);

    // W fragments once per block (volatile asm: resident for all 5 groups)
    unsigned rowb = (unsigned)((tn * 16 + lr) * 128 + quad * 16);
    u4 wr[8][2], wg[8][2];
    #pragma unroll
    for (int r = 0; r < 8; ++r) {
        WLOADP(wr[r][0], wr[r][1], WrB, rowb + (unsigned)r * 8192u);
        WLOADP(wg[r][0], wg[r][1], WgB, rowb + (unsigned)r * 8192u);
    }
    float bgv[8];
    #pragma unroll
    for (int r = 0; r < 8; ++r) bgv[r] = b_gate[r * 64 + tn * 16 + lr];
    f4 gmv = *(const f4*)(gamma + (tid & 15) * 4);
    f4 btv = *(const f4*)(beta + (tid & 15) * 4);

    for (int g = 0; g < NGRP; ++g) {
        int cb = g & 1;
        int n0 = nb0 + g * 16;
        if (g + 1 < NGRP) {
            STAGE_GRP(cb ^ 1, g + 1);
            // retire everything older than the newest 5 (= stage g+1):
            // stage(g) + W + any compiler vmem guaranteed complete.
            asm volatile("s_waitcnt vmcnt(5)" ::: "memory");
        } else {
            asm volatile("s_waitcnt vmcnt(0)" ::: "memory");
        }
        __builtin_amdgcn_sched_barrier(0);
        __builtin_amdgcn_s_barrier();      // stage(g) visible to all waves

        // A_h fragments from hsL[cb] (swizzled chunks)
        bf8 a_h[2];
        #pragma unroll
        for (int kb = 0; kb < 2; ++kb) {
            unsigned c0 = (unsigned)(kb * 8 + quad * 2)     ^ (unsigned)(lr & 7);
            unsigned c1 = (unsigned)(kb * 8 + quad * 2 + 1) ^ (unsigned)(lr & 7);
            f4 p0 = *(const f4*)((const char*)hsL[cb] + lr * 256 + c0 * 16);
            f4 p1 = *(const f4*)((const char*)hsL[cb] + lr * 256 + c1 * 16);
            bf8 a;
            #pragma unroll
            for (int j = 0; j < 4; ++j) a[j] = (short)bf16r(p0[j]);
            #pragma unroll
            for (int j = 0; j < 4; ++j) a[4 + j] = (short)bf16r(p1[j]);
            a_h[kb] = a;
        }

        // 8 relation MFMA phases (W from regs; a_p from psL[cb]) —
        // stage(g+1) flies underneath this.
        f4 acc = (f4){0.f, 0.f, 0.f, 0.f};
        #pragma unroll
        for (int r = 0; r < 8; ++r) {
            bf8 a_p[2];
            #pragma unroll
            for (int kb = 0; kb < 2; ++kb) {
                unsigned c = (unsigned)(kb * 4 + quad) ^ (unsigned)(lr & 7);
                a_p[kb] = *(const bf8*)((const char*)psL[cb] + lr * 1024 + r * 128 + c * 16);
            }
            f4 aggc = (f4){0.f, 0.f, 0.f, 0.f};
            f4 gacc = (f4){0.f, 0.f, 0.f, 0.f};
            aggc = __builtin_amdgcn_mfma_f32_16x16x32_bf16(a_p[0], asbf8(wr[r][0]), aggc, 0, 0, 0);
            gacc = __builtin_amdgcn_mfma_f32_16x16x32_bf16(a_h[0], asbf8(wg[r][0]), gacc, 0, 0, 0);
            aggc = __builtin_amdgcn_mfma_f32_16x16x32_bf16(a_p[1], asbf8(wr[r][1]), aggc, 0, 0, 0);
            gacc = __builtin_amdgcn_mfma_f32_16x16x32_bf16(a_h[1], asbf8(wg[r][1]), gacc, 0, 0, 0);
            #pragma unroll
            for (int j = 0; j < 4; ++j) {
                float gt = 1.f / (1.f + __expf(-(gacc[j] + bgv[r])));
                acc[j] += gt * aggc[j];
            }
        }
        __syncthreads();   // all waves done reading psL[cb] -> reuse as fp32

        float* ps_f = (float*)psL[cb];
        // t = h + acc/8 into ps_f rows 0..15; residual from swizzled hsL[cb]
        #pragma unroll
        for (int j = 0; j < 4; ++j) {
            int row = quad * 4 + j;
            int col = tn * 16 + lr;
            unsigned y = (unsigned)(row * 256 + col * 4);
            float hres = *(const float*)((const char*)hsL[cb] + (y ^ (((unsigned)(row & 7)) << 4)));
            ps_f[row * LDH + col] = hres + acc[j] * 0.125f;
        }
        __syncthreads();

        // LN + ReLU; o-tile into ps_f[OTB..) (disjoint region)
        {
            int row = tid >> 4, c = tid & 15;
            int n = n0 + row;
            f4 tv = *(const f4*)&ps_f[row * LDH + c * 4];
            float s1 = tv[0] + tv[1] + tv[2] + tv[3];
            float s2 = tv[0]*tv[0] + tv[1]*tv[1] + tv[2]*tv[2] + tv[3]*tv[3];
            #pragma unroll
            for (int off = 1; off <= 8; off <<= 1) {
                s1 += __shfl_xor(s1, off, 64);
                s2 += __shfl_xor(s2, off, 64);
            }
            float mu = s1 * (1.f / 64.f);
            float var = s2 * (1.f / 64.f) - mu * mu;
            float rs = rsqrtf(var + LN_EPS);
            f4 ov;
            #pragma unroll
            for (int j = 0; j < 4; ++j)
                ov[j] = fmaxf((tv[j] - mu) * rs * gmv[j] + btv[j], 0.f);
            if (!OUT)
                *(f4*)(hout + (size_t)n * 64 + c * 4) = ov;
            *(f4*)&ps_f[OTB + row * LDH + c * 4] = ov;
            if (EMIT) {
                u2 u;
                u[0] = (unsigned)bf16r(ov[0]) | ((unsigned)bf16r(ov[1]) << 16);
                u[1] = (unsigned)bf16r(ov[2]) | ((unsigned)bf16r(ov[3]) << 16);
                *(u2*)(hbf_out + (size_t)n * 64 + c * 4) = u;
            }
        }

        if (EMIT) {
            __syncthreads();
            if (w == 0) {   // next-layer attention pre-scores
                f4 sc = (f4){0.f, 0.f, 0.f, 0.f};
                #pragma unroll
                for (int kb = 0; kb < 2; ++kb) {
                    const float* p = &ps_f[OTB + lr * LDH + kb * 32 + quad * 8];
                    bf8 a;
                    #pragma unroll
                    for (int j = 0; j < 8; ++j) a[j] = (short)bf16r(p[j]);
                    const bf8* bw = (const bf8*)(WaB + lr * 64 + kb * 32 + quad * 8);
                    sc = __builtin_amdgcn_mfma_f32_16x16x32_bf16(a, *bw, sc, 0, 0, 0);
                }
                #pragma unroll
                for (int j = 0; j < 4; ++j) {
                    int n = n0 + quad * 4 + j;
                    if (lr < 8) ssrc_out[n * 8 + lr] = sc[j];
                    else        sdst_out[n * 8 + (lr - 8)] = sc[j];
                }
            }
        }

        if (OUT) {
            __syncthreads();
            f4 oc = (f4){0.f, 0.f, 0.f, 0.f};
            #pragma unroll
            for (int kb = 0; kb < 2; ++kb) {
                const float* p = &ps_f[OTB + lr * LDH + kb * 32 + quad * 8];
                bf8 a;
                #pragma unroll
                for (int j = 0; j < 8; ++j) a[j] = (short)bf16r(p[j]);
                const bf8* bw = (const bf8*)(WoB + ((tn * 16 + lr) * 64 + kb * 32 + quad * 8));
                oc = __builtin_amdgcn_mfma_f32_16x16x32_bf16(a, *bw, oc, 0, 0, 0);
            }
            float bo = b_out[tn * 16 + lr];
            #pragma unroll
            for (int j = 0; j < 4; ++j)
                outp[(size_t)(n0 + quad * 4 + j) * 64 + tn * 16 + lr] = oc[j] + bo;
        }
        __syncthreads();   // epilogue done: buffer reusable by stage(g+2)
    }
}

extern "C" void kernel_launch(void* const* d_in, const int* in_sizes, int n_in,
                              void* d_out, int out_size, void* d_ws, size_t ws_size,
                              hipStream_t stream) {
    const float* x      = (const float*)d_in[0];
    const int*   ei     = (const int*)d_in[1];
    const int*   et     = (const int*)d_in[2];
    const float* W_in   = (const float*)d_in[3];
    const float* b_in   = (const float*)d_in[4];
    const float* W_rel  = (const float*)d_in[5];
    const float* W_gate = (const float*)d_in[6];
    const float* b_gate = (const float*)d_in[7];
    const float* W_att  = (const float*)d_in[8];
    const float* b_att  = (const float*)d_in[9];
    const float* ln_g   = (const float*)d_in[10];
    const float* ln_b   = (const float*)d_in[11];
    const float* W_out  = (const float*)d_in[12];
    const float* b_out  = (const float*)d_in[13];
    float* out = (float*)d_out;

    float* h0 = (float*)d_out;          // ping-pong A (scratch until final layer)

    char* ws = (char*)d_ws;
    float* h1 = (float*)ws;                     ws += (size_t)NN * 64 * 4;
    unsigned short* hbfA = (unsigned short*)ws; ws += (size_t)NN * 64 * 2;
    unsigned short* hbfB = (unsigned short*)ws; ws += (size_t)NN * 64 * 2;
    float* s_src = (float*)ws;                  ws += (size_t)NN * 8 * 4;
    float* s_dst = (float*)ws;                  ws += (size_t)NN * 8 * 4;
    unsigned short* WrB = (unsigned short*)ws;  ws += (size_t)RR * 64 * 64 * 2;
    unsigned short* WgB = (unsigned short*)ws;  ws += (size_t)RR * 64 * 64 * 2;
    unsigned short* WaB = (unsigned short*)ws;  ws += 2048;
    unsigned short* WoB = (unsigned short*)ws;  ws += 8192;
    // contiguous zero region: counts + 3 per-layer dpart regions
    int* counts = (int*)ws;                     ws += (size_t)NR * 4;
    float* dpart = (float*)ws;                  ws += 3 * DSPREAD * 16 * 4;
    float* idn8G = (float*)ws;                  ws += 3 * 16 * 4;   // 8 used/layer
    int* offs = (int*)ws;                       ws += (size_t)NR * 4;
    int* bsum = (int*)ws;                       ws += 6400;
    int* rank = (int*)ws;                       ws += (size_t)EE * 4;
    u2* spack = (u2*)ws;                        ws += (size_t)EE * 8;
    u2* epack = (u2*)ws;                        ws += (size_t)EE * 8;
    unsigned short* psG = (unsigned short*)ws;  ws += (size_t)NR * 64 * 2;  // 51.2MB

    hipMemsetAsync(counts, 0, (size_t)NR * 4 + 3 * DSPREAD * 16 * 4, stream);
    cvt_w<<<128, 256, 0, stream>>>(W_rel, W_gate, W_att, W_out, WrB, WgB, WaB, WoB);
    edge_count<<<EE / 256, 256, 0, stream>>>(ei, et, counts, rank);
    scan1<<<NB, 256, 0, stream>>>(counts, offs, bsum);
    scan2<<<1, 1024, 0, stream>>>(bsum);
    edge_fill<<<EE / 256, 256, 0, stream>>>(ei, et, rank, offs, bsum, spack);
    proj_in<<<NN / 16, 256, 0, stream>>>(x, W_in, b_in, WaB, h0, hbfA, s_src, s_dst);

    const int tilesG = NN / 8;      // 6250 (gather grid, 8 nodes/block)
    const int tiles80 = NN / NPB;   // 625 (combine grid)
    float* hA = h0;  float* hB = h1;
    unsigned short* bfA = hbfA;  unsigned short* bfB = hbfB;
    for (int layer = 0; layer < LL; ++layer) {
        float* dpl = dpart + (size_t)layer * DSPREAD * 16;
        float* idn = idn8G + (size_t)layer * 16;
        edge_softmax2<<<EE / 256, 256, 0, stream>>>(spack, s_src, s_dst, b_att,
                                                    epack, dpl);
        denom_reduce<<<1, 256, 0, stream>>>(dpl, idn);
        gather_seg<<<tilesG, 256, 0, stream>>>(offs, bsum, epack, idn, bfA, psG);
        if (layer < LL - 1) {
            combine_dense<true, false><<<tiles80, 256, 0, stream>>>(
                hA, psG, WrB, WgB, WaB, WoB, b_gate,
                ln_g + layer * 64, ln_b + layer * 64,
                hB, bfB, s_src, s_dst, out, b_out);
        } else {
            combine_dense<false, true><<<tiles80, 256, 0, stream>>>(
                hA, psG, WrB, WgB, WaB, WoB, b_gate,
                ln_g + layer * 64, ln_b + layer * 64,
                hB, bfB, s_src, s_dst, out, b_out);
        }
        float* tf = hA; hA = hB; hB = tf;
        unsigned short* tb = bfA; bfA = bfB; bfB = tb;
    }
}

// Round 15
// 386.507 us; speedup vs baseline: 1.1822x; 1.0065x over previous
//
#include <hip/hip_runtime.h>
#include <math.h>

#define NN 50000
#define EE 800000
#define HH 64
#define RR 8
#define LL 3
#define NR (NN * RR)            // 400000 segments
#define NB ((NR + 255) / 256)   // 1563 scan blocks
#define LN_EPS 1e-5f
#define NEG_SLOPE 0.2f
#define LDH 68                  // fp32 row stride for t/o tiles in reused psL
#define OTB (16 * LDH)          // o-tile base (floats) inside ps_f
#define DSPREAD 64              // denom partial rows (distinct cachelines)
#define NPB 80                  // nodes per combine block (50000 = 625*80)
#define NGRP 5                  // 16-node groups per combine block

typedef __attribute__((ext_vector_type(8))) short bf8;
typedef __attribute__((ext_vector_type(4))) float f4;
typedef __attribute__((ext_vector_type(2))) float f2;
typedef __attribute__((ext_vector_type(8))) unsigned short us8;
typedef __attribute__((ext_vector_type(2))) unsigned int u2;
typedef __attribute__((ext_vector_type(4))) unsigned int u4;

// inline-asm W-fragment pair load: volatile => cannot be sunk/rematerialized
// (the r3/r4/r5 failure mode). Loaded ONCE per block, reused across 5 groups.
// SAFETY RULE (r10/r14 post-mortems): asm-loaded regs may be spilled by the
// compiler BEFORE the loads land (its model says asm outputs are ready at
// asm-end). Therefore this pattern is only valid in spill-free configs:
// (256,2) with measured VGPR=108. Do NOT raise occupancy on this kernel.
#define WLOADP(d0, d1, sbase, vbyte) \
    asm volatile("global_load_dwordx4 %0, %2, %3 offset:0\n\t" \
                 "global_load_dwordx4 %1, %2, %3 offset:64" \
        : "=&v"(d0), "=&v"(d1) : "v"(vbyte), "s"(sbase) : "memory")

__device__ __forceinline__ unsigned short bf16r(float f) {
    unsigned u = __float_as_uint(f);
    unsigned r = u + 0x7fffu + ((u >> 16) & 1u);
    return (unsigned short)(r >> 16);
}
__device__ __forceinline__ float bf2f(unsigned short u) {
    return __uint_as_float(((unsigned)u) << 16);
}
__device__ __forceinline__ bf8 asbf8(u4 v) {
    union { u4 a; bf8 b; } c; c.a = v; return c.b;
}
// fire-and-forget 16B global->LDS; completion via vmcnt accounting.
__device__ __forceinline__ void stage16(const void* g, void* l) {
    __builtin_amdgcn_global_load_lds(
        (const __attribute__((address_space(1))) void*)g,
        (__attribute__((address_space(3))) void*)l, 16, 0, 0);
}

// 16-node blocks: h = relu(x @ W_in^T + b_in) in fp32 via LDS;
// emit bf16 gather mirror; wave 0 computes s_src/s_dst via 2 MFMAs (WaB).
__global__ __launch_bounds__(256) void proj_in(
    const float* __restrict__ x, const float* __restrict__ W,
    const float* __restrict__ bias, const unsigned short* __restrict__ WaB,
    float* __restrict__ h, unsigned short* __restrict__ hbf,
    float* __restrict__ s_src, float* __restrict__ s_dst) {
    __shared__ float WT[64 * LDH];     // WT[i][k] = W[k][i]
    __shared__ float xs[16 * LDH];
    __shared__ float hs[16 * LDH];
    int tid = threadIdx.x;
    int n0 = blockIdx.x * 16;          // NN % 16 == 0
    #pragma unroll
    for (int s = 0; s < 16; ++s) {
        int idx = tid + 256 * s;
        int k = idx >> 6, i = idx & 63;
        WT[i * LDH + k] = W[idx];
    }
    int row = tid >> 4, cg = tid & 15;
    {
        f4 v = ((const f4*)x)[(size_t)(n0 + row) * 16 + cg];
        *(f4*)&xs[row * LDH + cg * 4] = v;
    }
    __syncthreads();
    f4 acc;
    {
        f4 b = *(const f4*)(bias + cg * 4);
        acc = b;
        #pragma unroll
        for (int i = 0; i < 64; ++i) {
            float xv = xs[row * LDH + i];
            f4 wt = *(const f4*)&WT[i * LDH + cg * 4];
            acc[0] += xv * wt[0];
            acc[1] += xv * wt[1];
            acc[2] += xv * wt[2];
            acc[3] += xv * wt[3];
        }
        #pragma unroll
        for (int j = 0; j < 4; ++j) acc[j] = fmaxf(acc[j], 0.f);
        int n = n0 + row;
        *(f4*)(h + (size_t)n * 64 + cg * 4) = acc;
        u2 u;
        u[0] = (unsigned)bf16r(acc[0]) | ((unsigned)bf16r(acc[1]) << 16);
        u[1] = (unsigned)bf16r(acc[2]) | ((unsigned)bf16r(acc[3]) << 16);
        *(u2*)(hbf + (size_t)n * 64 + cg * 4) = u;
        *(f4*)&hs[row * LDH + cg * 4] = acc;
    }
    __syncthreads();
    if (tid < 64) {      // wave 0: attention pre-scores via MFMA
        int lane = tid;
        int quad = lane >> 4, lr = lane & 15;
        f4 sc = (f4){0.f, 0.f, 0.f, 0.f};
        #pragma unroll
        for (int kb = 0; kb < 2; ++kb) {
            const float* p = &hs[lr * LDH + kb * 32 + quad * 8];
            bf8 a;
            #pragma unroll
            for (int j = 0; j < 8; ++j) a[j] = (short)bf16r(p[j]);
            const bf8* bw = (const bf8*)(WaB + lr * 64 + kb * 32 + quad * 8);
            sc = __builtin_amdgcn_mfma_f32_16x16x32_bf16(a, *bw, sc, 0, 0, 0);
        }
        #pragma unroll
        for (int j = 0; j < 4; ++j) {
            int n = n0 + quad * 4 + j;
            if (lr < 8) s_src[n * 8 + lr] = sc[j];
            else        s_dst[n * 8 + (lr - 8)] = sc[j];
        }
    }
}

// ---- one-time CSR build (compact, exact) ----
__global__ void edge_count(const int* __restrict__ ei, const int* __restrict__ et,
                           int* __restrict__ counts, int* __restrict__ rank) {
    int e = blockIdx.x * 256 + threadIdx.x;
    int d = ei[EE + e], t = et[e];
    rank[e] = atomicAdd(&counts[d * 8 + t], 1);
}

__global__ void scan1(const int* __restrict__ counts, int* __restrict__ offs,
                      int* __restrict__ bsum) {
    __shared__ int s[256];
    int tid = threadIdx.x;
    int i = blockIdx.x * 256 + tid;
    int v = (i < NR) ? counts[i] : 0;
    s[tid] = v; __syncthreads();
    for (int d = 1; d < 256; d <<= 1) {
        int x = (tid >= d) ? s[tid - d] : 0;
        __syncthreads();
        s[tid] += x;
        __syncthreads();
    }
    if (i < NR) offs[i] = s[tid] - v;   // local (per-block) exclusive prefix
    if (tid == 255) bsum[blockIdx.x] = s[255];
}

__global__ void scan2(int* __restrict__ bsum) {   // 1024 threads, 2 chunks
    __shared__ int s[1024];
    int tid = threadIdx.x;
    int carry = 0;
    for (int c0 = 0; c0 < NB; c0 += 1024) {
        int i = c0 + tid;
        int v = (i < NB) ? bsum[i] : 0;
        s[tid] = v; __syncthreads();
        for (int d = 1; d < 1024; d <<= 1) {
            int x = (tid >= d) ? s[tid - d] : 0;
            __syncthreads();
            s[tid] += x;
            __syncthreads();
        }
        if (i < NB) bsum[i] = carry + s[tid] - v;
        int tot = s[1023];
        __syncthreads();
        carry += tot;
    }
}

// spack[slot] = {src, seg}; slot = offs[seg] + bsum[seg>>8] + rank
__global__ void edge_fill(const int* __restrict__ ei, const int* __restrict__ et,
                          const int* __restrict__ rank, const int* __restrict__ offs,
                          const int* __restrict__ bsum, u2* __restrict__ spack) {
    int e = blockIdx.x * 256 + threadIdx.x;
    int s = ei[e], d = ei[EE + e], t = et[e];
    int seg = d * 8 + t;
    int slot = offs[seg] + bsum[seg >> 8] + rank[e];
    spack[slot] = (u2){(unsigned)s, (unsigned)seg};
}

// weights -> bf16: WrB/WgB [r][kout][kd]; WaB [16][64]; WoB [kout][kd]
__global__ void cvt_w(const float* __restrict__ Wr, const float* __restrict__ Wg,
                      const float* __restrict__ Wa, const float* __restrict__ Wo,
                      unsigned short* __restrict__ WrB, unsigned short* __restrict__ WgB,
                      unsigned short* __restrict__ WaB, unsigned short* __restrict__ WoB) {
    int i = blockIdx.x * 256 + threadIdx.x;   // 32768 total
    WrB[i] = bf16r(Wr[i]);
    WgB[i] = bf16r(Wg[i]);
    if (i < 1024) {
        int row = i >> 6, k = i & 63;
        float v = (row < 8) ? Wa[row * 128 + k] : Wa[(row - 8) * 128 + 64 + k];
        WaB[i] = bf16r(v);
    }
    if (i < 4096) WoB[i] = bf16r(Wo[i]);
}

// slot-parallel softmax; epack[slot] = {src, ex}; per-type denom partials
// (no max subtraction: |score|<~8, fp32-safe; softmax ratio shift-invariant)
__global__ void edge_softmax2(const u2* __restrict__ spack,
                              const float* __restrict__ s_src, const float* __restrict__ s_dst,
                              const float* __restrict__ b_att,
                              u2* __restrict__ epack, float* __restrict__ dpart) {
    __shared__ float lsum[4][8];
    int tid = threadIdx.x;
    if (tid < 32) lsum[tid >> 3][tid & 7] = 0.f;
    __syncthreads();
    int slot = blockIdx.x * 256 + tid;     // EE % 256 == 0
    u2 sp = spack[slot];
    int src = (int)sp[0];
    int seg = (int)sp[1];
    int t = seg & 7;
    float sc = s_src[src * 8 + t] + s_dst[seg] + b_att[t];
    sc = (sc >= 0.f) ? sc : NEG_SLOPE * sc;
    float ex = __expf(sc);
    epack[slot] = (u2){(unsigned)src, __float_as_uint(ex)};
    atomicAdd(&lsum[tid >> 6][t], ex);
    __syncthreads();
    if (tid < 8) {
        float v = lsum[0][tid] + lsum[1][tid] + lsum[2][tid] + lsum[3][tid];
        atomicAdd(&dpart[(blockIdx.x & (DSPREAD - 1)) * 16 + tid], v);
    }
}

// one-block reduce: dpart (64 rows x 16, types 0..7) -> idn8 = 1/sum
__global__ void denom_reduce(const float* __restrict__ dpartL,
                             float* __restrict__ idn8L) {
    __shared__ float sb[256];
    int t = threadIdx.x;
    int rb = t >> 3, ty = t & 7;
    float v = dpartL[rb * 16 + ty] + dpartL[(rb + 32) * 16 + ty];
    sb[t] = v; __syncthreads();
    for (int st = 128; st >= 8; st >>= 1) {
        if (t < st) sb[t] += sb[t + st];
        __syncthreads();
    }
    if (t < 8) idn8L[t] = 1.f / sb[t];
}

// K1: barrier-free, LDS-free segment gather — QUARTER-SPLIT (r13-verified):
// thread = (segment, 16-col quarter); (256,6) => 6 blocks/CU latency hiding.
// Block = 64 segments = 8 nodes; grid 6250. psG node-linear, byte-identical
// to the half-split image (combine untouched).
__global__ __launch_bounds__(256, 6) void gather_seg(
    const int* __restrict__ offs, const int* __restrict__ bsum,
    const u2* __restrict__ epack, const float* __restrict__ idn8L,
    const unsigned short* __restrict__ hbf_in,
    unsigned short* __restrict__ psG) {
    int tid = threadIdx.x;
    int segl = tid >> 2, qt = tid & 3;
    int sidx = blockIdx.x * 64 + segl;       // global (node,r) segment id
    int lo = offs[sidx] + bsum[sidx >> 8];
    int nxt = sidx + 1;
    int hi = (nxt < NR) ? (offs[nxt] + bsum[nxt >> 8]) : EE;
    int r = segl & 7, gn = segl >> 3;        // gn in 0..7 (8 nodes/block)

    // uniform-address scalar load of 8 inverse denoms; per-lane select
    f4 d0 = *(const f4*)(idn8L);
    f4 d1 = *(const f4*)(idn8L + 4);
    float i01 = (r & 1) ? d0[1] : d0[0];
    float i23 = (r & 1) ? d0[3] : d0[2];
    float i45 = (r & 1) ? d1[1] : d1[0];
    float i67 = (r & 1) ? d1[3] : d1[2];
    float i03 = (r & 2) ? i23 : i01;
    float i47 = (r & 2) ? i67 : i45;
    float idn = (r & 4) ? i47 : i03;

    f2 acc[8];
    #pragma unroll
    for (int i = 0; i < 8; ++i) acc[i] = (f2){0.f, 0.f};

    for (int s = lo; s < hi; s += 4) {
        int i1 = (s + 1 < hi) ? s + 1 : s;
        int i2 = (s + 2 < hi) ? s + 2 : s;
        int i3 = (s + 3 < hi) ? s + 3 : s;
        u2 pk0 = epack[s], pk1 = epack[i1], pk2 = epack[i2], pk3 = epack[i3];
        float a0 = __uint_as_float(pk0[1]);
        float a1 = (s + 1 < hi) ? __uint_as_float(pk1[1]) : 0.f;
        float a2 = (s + 2 < hi) ? __uint_as_float(pk2[1]) : 0.f;
        float a3 = (s + 3 < hi) ? __uint_as_float(pk3[1]) : 0.f;
        const u4* hp0 = (const u4*)(hbf_in + ((size_t)(int)pk0[0] << 6) + qt * 16);
        const u4* hp1 = (const u4*)(hbf_in + ((size_t)(int)pk1[0] << 6) + qt * 16);
        const u4* hp2 = (const u4*)(hbf_in + ((size_t)(int)pk2[0] << 6) + qt * 16);
        const u4* hp3 = (const u4*)(hbf_in + ((size_t)(int)pk3[0] << 6) + qt * 16);
        #pragma unroll
        for (int q = 0; q < 2; ++q) {
            u4 v0 = hp0[q], v1 = hp1[q], v2 = hp2[q], v3 = hp3[q];
            #pragma unroll
            for (int k = 0; k < 4; ++k) {
                f2 w0, w1, w2, w3;
                w0[0] = __uint_as_float(v0[k] << 16);
                w0[1] = __uint_as_float(v0[k] & 0xffff0000u);
                w1[0] = __uint_as_float(v1[k] << 16);
                w1[1] = __uint_as_float(v1[k] & 0xffff0000u);
                w2[0] = __uint_as_float(v2[k] << 16);
                w2[1] = __uint_as_float(v2[k] & 0xffff0000u);
                w3[0] = __uint_as_float(v3[k] << 16);
                w3[1] = __uint_as_float(v3[k] & 0xffff0000u);
                acc[q * 4 + k] += (f2){a0, a0} * w0;
                acc[q * 4 + k] += (f2){a1, a1} * w1;
                acc[q * 4 + k] += (f2){a2, a2} * w2;
                acc[q * 4 + k] += (f2){a3, a3} * w3;
            }
        }
    }

    // swizzled pack + store: chunk index (qt*2+q) ^ (gn&7) within the
    // (gn,r) 128B sub-row; combine reads LDS with the same XOR.
    unsigned short* base = psG + ((size_t)blockIdx.x << 12) + gn * 512 + r * 64;
    #pragma unroll
    for (int q = 0; q < 2; ++q) {
        us8 o;
        #pragma unroll
        for (int k = 0; k < 4; ++k) {
            o[2 * k]     = bf16r(acc[q * 4 + k][0] * idn);
            o[2 * k + 1] = bf16r(acc[q * 4 + k][1] * idn);
        }
        int c2 = (qt * 2 + q) ^ (gn & 7);
        *(us8*)(base + c2 * 8) = o;
    }
}

// stage one 16-node group (psG 16KB linear + hbuf 4KB src-swizzled) into
// buffer b. 5 global_load_lds per wave => vmcnt accounting unit = 5.
#define STAGE_GRP(b, g) do { \
    int n0s_ = nb0 + (g) * 16; \
    const char* ps_src_ = (const char*)psG + (size_t)n0s_ * 1024; \
    _Pragma("unroll") \
    for (int i_ = 0; i_ < 4; ++i_) { \
        unsigned off_ = i_ * 4096 + w * 1024; \
        stage16(ps_src_ + off_ + lane * 16, (char*)psL[b] + off_); \
    } \
    unsigned a_ = (unsigned)(w * 1024 + lane * 16); \
    unsigned sa_ = a_ ^ (((a_ >> 8) & 7u) << 4); \
    stage16((const char*)(hbuf + (size_t)n0s_ * 64) + sa_, (char*)hsL[b] + a_); \
} while (0)

// K2: dense combine (r8/r13-verified) — 80-node blocks (625), 5 groups,
// double-buffered staging, counted s_waitcnt vmcnt(5) + RAW s_barrier,
// W fragments resident once per block. (256,2) is REQUIRED: spill-free
// (VGPR 108 measured) which is the correctness precondition for the
// volatile-asm W loads (r14 post-mortem).
template<bool EMIT, bool OUT>
__global__ __launch_bounds__(256, 2) void combine_dense(
    const float* __restrict__ hbuf, const unsigned short* __restrict__ psG,
    const unsigned short* __restrict__ WrB, const unsigned short* __restrict__ WgB,
    const unsigned short* __restrict__ WaB, const unsigned short* __restrict__ WoB,
    const float* __restrict__ b_gate, const float* __restrict__ gamma,
    const float* __restrict__ beta, float* __restrict__ hout,
    unsigned short* __restrict__ hbf_out, float* __restrict__ ssrc_out,
    float* __restrict__ sdst_out, float* __restrict__ outp,
    const float* __restrict__ b_out) {
    __shared__ unsigned short psL[2][8192];   // 2 x 16KB a_p tiles / fp32 t,o scratch
    __shared__ float hsL[2][1024];            // 2 x 4KB h tiles (swizzled)
    int tid = threadIdx.x;
    int nb0 = blockIdx.x * NPB;
    int w = tid >> 6, lane = tid & 63;
    int quad = lane >> 4, lr = lane & 15;
    int tn = w;

    STAGE_GRP(0, 0);

    // W fragments once per block (volatile asm: resident for all 5 groups)
    unsigned rowb = (unsigned)((tn * 16 + lr) * 128 + quad * 16);
    u4 wr[8][2], wg[8][2];
    #pragma unroll
    for (int r = 0; r < 8; ++r) {
        WLOADP(wr[r][0], wr[r][1], WrB, rowb + (unsigned)r * 8192u);
        WLOADP(wg[r][0], wg[r][1], WgB, rowb + (unsigned)r * 8192u);
    }
    float bgv[8];
    #pragma unroll
    for (int r = 0; r < 8; ++r) bgv[r] = b_gate[r * 64 + tn * 16 + lr];
    f4 gmv = *(const f4*)(gamma + (tid & 15) * 4);
    f4 btv = *(const f4*)(beta + (tid & 15) * 4);

    for (int g = 0; g < NGRP; ++g) {
        int cb = g & 1;
        int n0 = nb0 + g * 16;
        if (g + 1 < NGRP) {
            STAGE_GRP(cb ^ 1, g + 1);
            // retire everything older than the newest 5 (= stage g+1):
            // stage(g) + W + any compiler vmem guaranteed complete.
            asm volatile("s_waitcnt vmcnt(5)" ::: "memory");
        } else {
            asm volatile("s_waitcnt vmcnt(0)" ::: "memory");
        }
        __builtin_amdgcn_sched_barrier(0);
        __builtin_amdgcn_s_barrier();      // stage(g) visible to all waves

        // A_h fragments from hsL[cb] (swizzled chunks)
        bf8 a_h[2];
        #pragma unroll
        for (int kb = 0; kb < 2; ++kb) {
            unsigned c0 = (unsigned)(kb * 8 + quad * 2)     ^ (unsigned)(lr & 7);
            unsigned c1 = (unsigned)(kb * 8 + quad * 2 + 1) ^ (unsigned)(lr & 7);
            f4 p0 = *(const f4*)((const char*)hsL[cb] + lr * 256 + c0 * 16);
            f4 p1 = *(const f4*)((const char*)hsL[cb] + lr * 256 + c1 * 16);
            bf8 a;
            #pragma unroll
            for (int j = 0; j < 4; ++j) a[j] = (short)bf16r(p0[j]);
            #pragma unroll
            for (int j = 0; j < 4; ++j) a[4 + j] = (short)bf16r(p1[j]);
            a_h[kb] = a;
        }

        // 8 relation MFMA phases (W from regs; a_p from psL[cb]) —
        // stage(g+1) flies underneath this.
        f4 acc = (f4){0.f, 0.f, 0.f, 0.f};
        #pragma unroll
        for (int r = 0; r < 8; ++r) {
            bf8 a_p[2];
            #pragma unroll
            for (int kb = 0; kb < 2; ++kb) {
                unsigned c = (unsigned)(kb * 4 + quad) ^ (unsigned)(lr & 7);
                a_p[kb] = *(const bf8*)((const char*)psL[cb] + lr * 1024 + r * 128 + c * 16);
            }
            f4 aggc = (f4){0.f, 0.f, 0.f, 0.f};
            f4 gacc = (f4){0.f, 0.f, 0.f, 0.f};
            aggc = __builtin_amdgcn_mfma_f32_16x16x32_bf16(a_p[0], asbf8(wr[r][0]), aggc, 0, 0, 0);
            gacc = __builtin_amdgcn_mfma_f32_16x16x32_bf16(a_h[0], asbf8(wg[r][0]), gacc, 0, 0, 0);
            aggc = __builtin_amdgcn_mfma_f32_16x16x32_bf16(a_p[1], asbf8(wr[r][1]), aggc, 0, 0, 0);
            gacc = __builtin_amdgcn_mfma_f32_16x16x32_bf16(a_h[1], asbf8(wg[r][1]), gacc, 0, 0, 0);
            #pragma unroll
            for (int j = 0; j < 4; ++j) {
                float gt = 1.f / (1.f + __expf(-(gacc[j] + bgv[r])));
                acc[j] += gt * aggc[j];
            }
        }
        __syncthreads();   // all waves done reading psL[cb] -> reuse as fp32

        float* ps_f = (float*)psL[cb];
        // t = h + acc/8 into ps_f rows 0..15; residual from swizzled hsL[cb]
        #pragma unroll
        for (int j = 0; j < 4; ++j) {
            int row = quad * 4 + j;
            int col = tn * 16 + lr;
            unsigned y = (unsigned)(row * 256 + col * 4);
            float hres = *(const float*)((const char*)hsL[cb] + (y ^ (((unsigned)(row & 7)) << 4)));
            ps_f[row * LDH + col] = hres + acc[j] * 0.125f;
        }
        __syncthreads();

        // LN + ReLU; o-tile into ps_f[OTB..) (disjoint region)
        {
            int row = tid >> 4, c = tid & 15;
            int n = n0 + row;
            f4 tv = *(const f4*)&ps_f[row * LDH + c * 4];
            float s1 = tv[0] + tv[1] + tv[2] + tv[3];
            float s2 = tv[0]*tv[0] + tv[1]*tv[1] + tv[2]*tv[2] + tv[3]*tv[3];
            #pragma unroll
            for (int off = 1; off <= 8; off <<= 1) {
                s1 += __shfl_xor(s1, off, 64);
                s2 += __shfl_xor(s2, off, 64);
            }
            float mu = s1 * (1.f / 64.f);
            float var = s2 * (1.f / 64.f) - mu * mu;
            float rs = rsqrtf(var + LN_EPS);
            f4 ov;
            #pragma unroll
            for (int j = 0; j < 4; ++j)
                ov[j] = fmaxf((tv[j] - mu) * rs * gmv[j] + btv[j], 0.f);
            if (!OUT)
                *(f4*)(hout + (size_t)n * 64 + c * 4) = ov;
            *(f4*)&ps_f[OTB + row * LDH + c * 4] = ov;
            if (EMIT) {
                u2 u;
                u[0] = (unsigned)bf16r(ov[0]) | ((unsigned)bf16r(ov[1]) << 16);
                u[1] = (unsigned)bf16r(ov[2]) | ((unsigned)bf16r(ov[3]) << 16);
                *(u2*)(hbf_out + (size_t)n * 64 + c * 4) = u;
            }
        }

        if (EMIT) {
            __syncthreads();
            if (w == 0) {   // next-layer attention pre-scores
                f4 sc = (f4){0.f, 0.f, 0.f, 0.f};
                #pragma unroll
                for (int kb = 0; kb < 2; ++kb) {
                    const float* p = &ps_f[OTB + lr * LDH + kb * 32 + quad * 8];
                    bf8 a;
                    #pragma unroll
                    for (int j = 0; j < 8; ++j) a[j] = (short)bf16r(p[j]);
                    const bf8* bw = (const bf8*)(WaB + lr * 64 + kb * 32 + quad * 8);
                    sc = __builtin_amdgcn_mfma_f32_16x16x32_bf16(a, *bw, sc, 0, 0, 0);
                }
                #pragma unroll
                for (int j = 0; j < 4; ++j) {
                    int n = n0 + quad * 4 + j;
                    if (lr < 8) ssrc_out[n * 8 + lr] = sc[j];
                    else        sdst_out[n * 8 + (lr - 8)] = sc[j];
                }
            }
        }

        if (OUT) {
            __syncthreads();
            f4 oc = (f4){0.f, 0.f, 0.f, 0.f};
            #pragma unroll
            for (int kb = 0; kb < 2; ++kb) {
                const float* p = &ps_f[OTB + lr * LDH + kb * 32 + quad * 8];
                bf8 a;
                #pragma unroll
                for (int j = 0; j < 8; ++j) a[j] = (short)bf16r(p[j]);
                const bf8* bw = (const bf8*)(WoB + ((tn * 16 + lr) * 64 + kb * 32 + quad * 8));
                oc = __builtin_amdgcn_mfma_f32_16x16x32_bf16(a, *bw, oc, 0, 0, 0);
            }
            float bo = b_out[tn * 16 + lr];
            #pragma unroll
            for (int j = 0; j < 4; ++j)
                outp[(size_t)(n0 + quad * 4 + j) * 64 + tn * 16 + lr] = oc[j] + bo;
        }
        __syncthreads();   // epilogue done: buffer reusable by stage(g+2)
    }
}

extern "C" void kernel_launch(void* const* d_in, const int* in_sizes, int n_in,
                              void* d_out, int out_size, void* d_ws, size_t ws_size,
                              hipStream_t stream) {
    const float* x      = (const float*)d_in[0];
    const int*   ei     = (const int*)d_in[1];
    const int*   et     = (const int*)d_in[2];
    const float* W_in   = (const float*)d_in[3];
    const float* b_in   = (const float*)d_in[4];
    const float* W_rel  = (const float*)d_in[5];
    const float* W_gate = (const float*)d_in[6];
    const float* b_gate = (const float*)d_in[7];
    const float* W_att  = (const float*)d_in[8];
    const float* b_att  = (const float*)d_in[9];
    const float* ln_g   = (const float*)d_in[10];
    const float* ln_b   = (const float*)d_in[11];
    const float* W_out  = (const float*)d_in[12];
    const float* b_out  = (const float*)d_in[13];
    float* out = (float*)d_out;

    float* h0 = (float*)d_out;          // ping-pong A (scratch until final layer)

    char* ws = (char*)d_ws;
    float* h1 = (float*)ws;                     ws += (size_t)NN * 64 * 4;
    unsigned short* hbfA = (unsigned short*)ws; ws += (size_t)NN * 64 * 2;
    unsigned short* hbfB = (unsigned short*)ws; ws += (size_t)NN * 64 * 2;
    float* s_src = (float*)ws;                  ws += (size_t)NN * 8 * 4;
    float* s_dst = (float*)ws;                  ws += (size_t)NN * 8 * 4;
    unsigned short* WrB = (unsigned short*)ws;  ws += (size_t)RR * 64 * 64 * 2;
    unsigned short* WgB = (unsigned short*)ws;  ws += (size_t)RR * 64 * 64 * 2;
    unsigned short* WaB = (unsigned short*)ws;  ws += 2048;
    unsigned short* WoB = (unsigned short*)ws;  ws += 8192;
    // contiguous zero region: counts + 3 per-layer dpart regions
    int* counts = (int*)ws;                     ws += (size_t)NR * 4;
    float* dpart = (float*)ws;                  ws += 3 * DSPREAD * 16 * 4;
    float* idn8G = (float*)ws;                  ws += 3 * 16 * 4;   // 8 used/layer
    int* offs = (int*)ws;                       ws += (size_t)NR * 4;
    int* bsum = (int*)ws;                       ws += 6400;
    int* rank = (int*)ws;                       ws += (size_t)EE * 4;
    u2* spack = (u2*)ws;                        ws += (size_t)EE * 8;
    u2* epack = (u2*)ws;                        ws += (size_t)EE * 8;
    unsigned short* psG = (unsigned short*)ws;  ws += (size_t)NR * 64 * 2;  // 51.2MB

    hipMemsetAsync(counts, 0, (size_t)NR * 4 + 3 * DSPREAD * 16 * 4, stream);
    cvt_w<<<128, 256, 0, stream>>>(W_rel, W_gate, W_att, W_out, WrB, WgB, WaB, WoB);
    edge_count<<<EE / 256, 256, 0, stream>>>(ei, et, counts, rank);
    scan1<<<NB, 256, 0, stream>>>(counts, offs, bsum);
    scan2<<<1, 1024, 0, stream>>>(bsum);
    edge_fill<<<EE / 256, 256, 0, stream>>>(ei, et, rank, offs, bsum, spack);
    proj_in<<<NN / 16, 256, 0, stream>>>(x, W_in, b_in, WaB, h0, hbfA, s_src, s_dst);

    const int tilesG = NN / 8;      // 6250 (gather grid, 8 nodes/block)
    const int tiles80 = NN / NPB;   // 625 (combine grid)
    float* hA = h0;  float* hB = h1;
    unsigned short* bfA = hbfA;  unsigned short* bfB = hbfB;
    for (int layer = 0; layer < LL; ++layer) {
        float* dpl = dpart + (size_t)layer * DSPREAD * 16;
        float* idn = idn8G + (size_t)layer * 16;
        edge_softmax2<<<EE / 256, 256, 0, stream>>>(spack, s_src, s_dst, b_att,
                                                    epack, dpl);
        denom_reduce<<<1, 256, 0, stream>>>(dpl, idn);
        gather_seg<<<tilesG, 256, 0, stream>>>(offs, bsum, epack, idn, bfA, psG);
        if (layer < LL - 1) {
            combine_dense<true, false><<<tiles80, 256, 0, stream>>>(
                hA, psG, WrB, WgB, WaB, WoB, b_gate,
                ln_g + layer * 64, ln_b + layer * 64,
                hB, bfB, s_src, s_dst, out, b_out);
        } else {
            combine_dense<false, true><<<tiles80, 256, 0, stream>>>(
                hA, psG, WrB, WgB, WaB, WoB, b_gate,
                ln_g + layer * 64, ln_b + layer * 64,
                hB, bfB, s_src, s_dst, out, b_out);
        }
        float* tf = hA; hA = hB; hB = tf;
        unsigned short* tb = bfA; bfA = bfB; bfB = tb;
    }
}